// Round 4
// baseline (141273.865 us; speedup 1.0000x reference)
//
#include <hip/hip_runtime.h>
#include <hip/hip_bf16.h>

#define TPB 256

// ================= edge list construction (original order) =================
__global__ void build_edges_k(const int* __restrict__ ea, const int* __restrict__ eb,
                              const int* __restrict__ pb,
                              int Ea, int Eb, int NC, int Na,
                              int* __restrict__ src, int* __restrict__ dst) {
    int e = blockIdx.x * TPB + threadIdx.x;
    int E = Ea + Eb + 2 * NC;
    if (e >= E) return;
    int s, d;
    if (e < Ea) { s = ea[2*e]; d = ea[2*e+1]; }
    else if (e < Ea + Eb) { int i = e - Ea; s = eb[2*i] + Na; d = eb[2*i+1] + Na; }
    else if (e < Ea + Eb + NC) { int c = e - Ea - Eb; s = pb[c]; d = pb[NC + c] + Na; }
    else { int c = e - Ea - Eb - NC; s = pb[NC + c] + Na; d = pb[c]; }
    src[e] = s; dst[e] = d;
}

__global__ void count_k(const int* __restrict__ key, int* __restrict__ counts, int E) {
    int e = blockIdx.x * TPB + threadIdx.x;
    if (e < E) atomicAdd(&counts[key[e]], 1);
}

// ---- exclusive scan over counts[0..N-1] -> offs ----
__global__ void scan1_k(const int* __restrict__ counts, int* __restrict__ offs,
                        int* __restrict__ partials, int N) {
    __shared__ int sdata[TPB];
    int tid = threadIdx.x;
    int base = blockIdx.x * 1024;
    int v[4]; int s = 0;
    #pragma unroll
    for (int r = 0; r < 4; r++) {
        int idx = base + tid * 4 + r;
        v[r] = (idx < N) ? counts[idx] : 0;
        s += v[r];
    }
    sdata[tid] = s;
    __syncthreads();
    for (int o = 1; o < TPB; o <<= 1) {
        int t = (tid >= o) ? sdata[tid - o] : 0;
        __syncthreads();
        sdata[tid] += t;
        __syncthreads();
    }
    if (tid == TPB - 1) partials[blockIdx.x] = sdata[TPB - 1];
    int run = sdata[tid] - s;
    #pragma unroll
    for (int r = 0; r < 4; r++) {
        int idx = base + tid * 4 + r;
        if (idx < N) offs[idx] = run;
        run += v[r];
    }
}

__global__ void scan2_k(int* __restrict__ partials, int nPart) {
    if (blockIdx.x == 0 && threadIdx.x == 0) {
        int acc = 0;
        for (int i = 0; i < nPart; i++) { int t = partials[i]; partials[i] = acc; acc += t; }
    }
}

__global__ void scan3_k(int* __restrict__ offs, const int* __restrict__ partials, int N, int E) {
    int i = blockIdx.x * TPB + threadIdx.x;
    if (i < N) offs[i] += partials[i >> 10];
    else if (i == N) offs[N] = E;
}

// fill: edges sorted by SRC. srcS/dstS/eOrigS in sorted order.
__global__ void fill_k(const int* __restrict__ src, const int* __restrict__ dst,
                       const int* __restrict__ offs, int* __restrict__ cursor,
                       int* __restrict__ srcS, int* __restrict__ dstS,
                       int* __restrict__ eOrigS, int E) {
    int e = blockIdx.x * TPB + threadIdx.x;
    if (e >= E) return;
    int s = src[e];
    int p = offs[s] + atomicAdd(&cursor[s], 1);
    srcS[p] = s;
    dstS[p] = dst[e];
    eOrigS[p] = e;
}

// ================= h0 (bf16, src-sorted order) + scatter of h_1 = h0 into agg =================
__global__ void h0s_k(const float* __restrict__ xa, const float* __restrict__ xb,
                      const float* __restrict__ efa, const float* __restrict__ efb,
                      const int* __restrict__ srcS, const int* __restrict__ dstS,
                      const int* __restrict__ eOrigS,
                      int Ea, int Eb, int Na, int E,
                      const float* __restrict__ W_in, const float* __restrict__ b_in,
                      __hip_bfloat16* __restrict__ h0s, float* __restrict__ agg) {
    __shared__ float Wl[6 * 64];
    __shared__ float bl[64];
    for (int t = threadIdx.x; t < 6 * 64; t += TPB) Wl[t] = W_in[t];
    if (threadIdx.x < 64) bl[threadIdx.x] = b_in[threadIdx.x];
    __syncthreads();
    long long gid = (long long)blockIdx.x * TPB + threadIdx.x;
    if (gid >= (long long)E * 64) return;
    int k = (int)(gid >> 6), j = (int)(gid & 63);
    int e = eOrigS[k];
    int s = srcS[k];
    const float* xp = (s < Na) ? (xa + (size_t)s * 5) : (xb + (size_t)(s - Na) * 5);
    float efv = (e < Ea) ? efa[e] : ((e < Ea + Eb) ? efb[e - Ea] : 999.0f);
    float acc = bl[j];
    #pragma unroll
    for (int i = 0; i < 5; i++) acc += xp[i] * Wl[i * 64 + j];
    acc += efv * Wl[5 * 64 + j];
    acc = fmaxf(acc, 0.0f);
    h0s[(size_t)gid] = __float2bfloat16(acc);
    atomicAdd(&agg[(size_t)dstS[k] * 64 + j], acc);
}

// ================= per-node GEMM: aggW(bf16) = agg @ W_msg + b_msg; re-zeroes agg =================
__global__ __launch_bounds__(TPB) void nodegemm_k(float* __restrict__ agg,
                                                  const float* __restrict__ W_msg,
                                                  const float* __restrict__ b_msg,
                                                  __hip_bfloat16* __restrict__ aggW, int N) {
    __shared__ __align__(16) float Wl[64 * 64];
    __shared__ float bl[64];
    __shared__ __align__(16) float actL[64 * 64];
    int tid = threadIdx.x;
    for (int t = tid; t < 4096; t += TPB) Wl[t] = W_msg[t];
    if (tid < 64) bl[tid] = b_msg[tid];
    size_t base = (size_t)blockIdx.x * 4096;
    size_t lim = (size_t)N * 64;
    for (int t = tid; t < 4096; t += TPB) {
        size_t g = base + t;
        float v = 0.0f;
        if (g < lim) { v = agg[g]; agg[g] = 0.0f; }
        actL[t] = v;
    }
    __syncthreads();
    int j = tid & 63;
    int n0 = (tid >> 6) * 16;
    float acc[16];
    #pragma unroll
    for (int k = 0; k < 16; k++) acc[k] = bl[j];
    const float4* act4 = (const float4*)actL;
    #pragma unroll
    for (int i4 = 0; i4 < 16; i4++) {
        float w0 = Wl[(4 * i4 + 0) * 64 + j];
        float w1 = Wl[(4 * i4 + 1) * 64 + j];
        float w2 = Wl[(4 * i4 + 2) * 64 + j];
        float w3 = Wl[(4 * i4 + 3) * 64 + j];
        #pragma unroll
        for (int k = 0; k < 16; k++) {
            float4 a = act4[(n0 + k) * 16 + i4];
            acc[k] += a.x * w0 + a.y * w1 + a.z * w2 + a.w * w3;
        }
    }
    #pragma unroll
    for (int k = 0; k < 16; k++) {
        size_t g2 = base + (size_t)(n0 + k) * 64 + j;
        if (g2 < lim) aggW[g2] = __float2bfloat16(acc[k]);
    }
}

// ================= edge step: h = relu(h0 + aggW[src]); atomic scatter into agg =================
// thread = (sorted-edge k, 8-channel group g).  MODE 1: normal; MODE 2: + hsave for candidates.
template<int MODE>
__global__ __launch_bounds__(TPB) void edge_bf16_k(const uint4* __restrict__ h0s16,
                                                   const uint4* __restrict__ aggW16,
                                                   const int* __restrict__ srcS,
                                                   const int* __restrict__ dstS,
                                                   const int* __restrict__ eOrigS,
                                                   float* __restrict__ agg,
                                                   float* __restrict__ hsave,
                                                   int E, int off) {
    long long gid = (long long)blockIdx.x * TPB + threadIdx.x;
    if (gid >= (long long)E * 8) return;
    int k = (int)(gid >> 3), g = (int)(gid & 7);
    int s = srcS[k];
    uint4 hv = h0s16[(size_t)k * 8 + g];
    uint4 wv = aggW16[(size_t)s * 8 + g];
    float v[8];
    {
        unsigned hu[4] = {hv.x, hv.y, hv.z, hv.w};
        unsigned wu[4] = {wv.x, wv.y, wv.z, wv.w};
        #pragma unroll
        for (int i = 0; i < 4; i++) {
            float hlo = __uint_as_float(hu[i] << 16);
            float hhi = __uint_as_float(hu[i] & 0xffff0000u);
            float wlo = __uint_as_float(wu[i] << 16);
            float whi = __uint_as_float(wu[i] & 0xffff0000u);
            v[2*i]   = fmaxf(hlo + wlo, 0.0f);
            v[2*i+1] = fmaxf(hhi + whi, 0.0f);
        }
    }
    float* ap = agg + (size_t)dstS[k] * 64 + g * 8;
    #pragma unroll
    for (int i = 0; i < 8; i++) atomicAdd(&ap[i], v[i]);
    if (MODE == 2) {
        int eo = eOrigS[k];
        if (eo >= off) {
            float* hp = hsave + (size_t)(eo - off) * 64 + g * 8;
            #pragma unroll
            for (int i = 0; i < 8; i++) hp[i] = v[i];
        }
    }
}

// ================= node_h = relu([x, agg] @ W_node + b_node) =================
__global__ void nodeh_k(const float* __restrict__ xa, const float* __restrict__ xb,
                        int Na, int N,
                        const float* __restrict__ agg,
                        const float* __restrict__ W_node, const float* __restrict__ b_node,
                        float* __restrict__ node_h) {
    __shared__ float Wl[69 * 32];
    __shared__ float bl[32];
    for (int t = threadIdx.x; t < 69 * 32; t += TPB) Wl[t] = W_node[t];
    if (threadIdx.x < 32) bl[threadIdx.x] = b_node[threadIdx.x];
    __syncthreads();
    long long gid = (long long)blockIdx.x * TPB + threadIdx.x;
    if (gid >= (long long)N * 32) return;
    int n = (int)(gid >> 5), j = (int)(gid & 31);
    const float* xp = (n < Na) ? (xa + (size_t)n * 5) : (xb + (size_t)(n - Na) * 5);
    float acc = bl[j];
    #pragma unroll
    for (int i = 0; i < 5; i++) acc += xp[i] * Wl[i * 32 + j];
    const float4* a4 = (const float4*)(agg + (size_t)n * 64);
    #pragma unroll
    for (int i4 = 0; i4 < 16; i4++) {
        float4 a = a4[i4];
        acc += a.x * Wl[(5 + 4 * i4 + 0) * 32 + j];
        acc += a.y * Wl[(5 + 4 * i4 + 1) * 32 + j];
        acc += a.z * Wl[(5 + 4 * i4 + 2) * 32 + j];
        acc += a.w * Wl[(5 + 4 * i4 + 3) * 32 + j];
    }
    node_h[gid] = fmaxf(acc, 0.0f);
}

// ================= MLP head =================
#define TM2 32
#define MSTR 260

__device__ __forceinline__ void mlp_layer2(const float* __restrict__ W, const float* __restrict__ b,
                                           int in, int out, int lgout,
                                           const float* __restrict__ A, float* __restrict__ B) {
    int pairs = out * (TM2 / 8);
    const float4* a4b = (const float4*)A;
    for (int p = threadIdx.x; p < pairs; p += TPB) {
        int j = p & (out - 1);
        int r0 = (p >> lgout) * 8;
        float acc[8];
        float bj = b[j];
        #pragma unroll
        for (int r = 0; r < 8; r++) acc[r] = bj;
        for (int i4 = 0; i4 < (in >> 2); i4++) {
            int i = i4 * 4;
            float w0 = W[(i + 0) * out + j];
            float w1 = W[(i + 1) * out + j];
            float w2 = W[(i + 2) * out + j];
            float w3 = W[(i + 3) * out + j];
            #pragma unroll
            for (int r = 0; r < 8; r++) {
                float4 a = a4b[(r0 + r) * 65 + i4];
                acc[r] += a.x * w0 + a.y * w1 + a.z * w2 + a.w * w3;
            }
        }
        #pragma unroll
        for (int r = 0; r < 8; r++) B[(r0 + r) * MSTR + j] = fmaxf(acc[r], 0.0f);
    }
    __syncthreads();
}

__global__ __launch_bounds__(TPB) void mlp2_k(const float* __restrict__ node_h,
                                              const float* __restrict__ hsave,
                                              const int* __restrict__ pb, int NC, int Na,
                                              const float* __restrict__ W1, const float* __restrict__ b1,
                                              const float* __restrict__ W2, const float* __restrict__ b2,
                                              const float* __restrict__ W3, const float* __restrict__ b3,
                                              const float* __restrict__ W4, const float* __restrict__ b4,
                                              const float* __restrict__ W5, const float* __restrict__ b5,
                                              const float* __restrict__ W6, const float* __restrict__ b6,
                                              float* __restrict__ out) {
    __shared__ __align__(16) float A[TM2 * MSTR];
    __shared__ __align__(16) float B[TM2 * MSTR];
    int c0 = blockIdx.x * TM2;
    for (int idx = threadIdx.x; idx < TM2 * 128; idx += TPB) {
        int r = idx >> 7, col = idx & 127;
        int c = c0 + r;
        float v = 0.0f;
        if (c < NC) {
            if (col < 32) v = node_h[(size_t)pb[c] * 32 + col];
            else if (col < 64) v = node_h[(size_t)(Na + pb[NC + c]) * 32 + (col - 32)];
            else v = hsave[(size_t)c * 64 + (col - 64)] + hsave[(size_t)(NC + c) * 64 + (col - 64)];
        }
        A[r * MSTR + col] = v;
    }
    __syncthreads();
    mlp_layer2(W1, b1, 128, 128, 7, A, B);
    mlp_layer2(W2, b2, 128, 256, 8, B, A);
    mlp_layer2(W3, b3, 256, 256, 8, A, B);
    mlp_layer2(W4, b4, 256, 128, 7, B, A);
    mlp_layer2(W5, b5, 128, 64, 6, A, B);
    if (threadIdx.x < TM2) {
        int r = threadIdx.x, c = c0 + r;
        if (c < NC) {
            float z[4];
            #pragma unroll
            for (int k = 0; k < 4; k++) {
                float acc = b6[k];
                for (int i = 0; i < 64; i++) acc += B[r * MSTR + i] * W6[i * 4 + k];
                z[k] = acc;
            }
            float m = fmaxf(fmaxf(z[0], z[1]), fmaxf(z[2], z[3]));
            float e0 = expf(z[0] - m), e1 = expf(z[1] - m), e2 = expf(z[2] - m), e3 = expf(z[3] - m);
            float inv = 1.0f / (e0 + e1 + e2 + e3);
            int am = 0; float bm = z[0];
            if (z[1] > bm) { bm = z[1]; am = 1; }
            if (z[2] > bm) { bm = z[2]; am = 2; }
            if (z[3] > bm) { bm = z[3]; am = 3; }
            out[(size_t)c * 3 + 0] = (float)pb[c];
            out[(size_t)c * 3 + 1] = (float)pb[NC + c];
            out[(size_t)c * 3 + 2] = (float)am;
            float* po = out + (size_t)NC * 3 + (size_t)c * 4;
            po[0] = e0 * inv; po[1] = e1 * inv; po[2] = e2 * inv; po[3] = e3 * inv;
        }
    }
}

extern "C" void kernel_launch(void* const* d_in, const int* in_sizes, int n_in,
                              void* d_out, int out_size, void* d_ws, size_t ws_size,
                              hipStream_t stream) {
    const float* xa   = (const float*)d_in[0];
    const float* efa  = (const float*)d_in[1];
    const int*   ea   = (const int*)d_in[2];
    const float* xb   = (const float*)d_in[3];
    const float* efb  = (const float*)d_in[4];
    const int*   eb   = (const int*)d_in[5];
    const int*   pb   = (const int*)d_in[6];
    const float* W_in   = (const float*)d_in[7];
    const float* b_in   = (const float*)d_in[8];
    const float* W_msg  = (const float*)d_in[9];
    const float* b_msg  = (const float*)d_in[10];
    const float* W_node = (const float*)d_in[11];
    const float* b_node = (const float*)d_in[12];
    const float* W1 = (const float*)d_in[13]; const float* b1 = (const float*)d_in[14];
    const float* W2 = (const float*)d_in[15]; const float* b2 = (const float*)d_in[16];
    const float* W3 = (const float*)d_in[17]; const float* b3 = (const float*)d_in[18];
    const float* W4 = (const float*)d_in[19]; const float* b4 = (const float*)d_in[20];
    const float* W5 = (const float*)d_in[21]; const float* b5 = (const float*)d_in[22];
    const float* W6 = (const float*)d_in[23]; const float* b6 = (const float*)d_in[24];

    int Na = in_sizes[0] / 5;
    int Ea = in_sizes[2] / 2;
    int Nb = in_sizes[3] / 5;
    int Eb = in_sizes[5] / 2;
    int NC = in_sizes[6] / 2;
    int N = Na + Nb;
    int E = Ea + Eb + 2 * NC;
    int off = Ea + Eb;
    int nPart = (N + 1023) / 1024;

    char* p = (char*)d_ws;
    auto alloc = [&](size_t bytes) { char* r = p; p += (bytes + 255) & ~(size_t)255; return r; };
    int*   srcO   = (int*)alloc((size_t)E * 4);
    int*   dstO   = (int*)alloc((size_t)E * 4);
    int*   counts = (int*)alloc((size_t)N * 4);
    int*   offs   = (int*)alloc((size_t)(N + 1) * 4);
    int*   cursor = (int*)alloc((size_t)N * 4);
    int*   parts  = (int*)alloc((size_t)nPart * 4);
    int*   srcS   = (int*)alloc((size_t)E * 4);
    int*   dstS   = (int*)alloc((size_t)E * 4);
    int*   eOrigS = (int*)alloc((size_t)E * 4);
    __hip_bfloat16* h0s  = (__hip_bfloat16*)alloc((size_t)E * 64 * 2);
    float* agg    = (float*)alloc((size_t)N * 64 * 4);
    __hip_bfloat16* aggW = (__hip_bfloat16*)alloc((size_t)N * 64 * 2);
    float* hsave  = (float*)alloc((size_t)2 * NC * 64 * 4);
    float* nodeh  = (float*)alloc((size_t)N * 32 * 4);
    if ((size_t)(p - (char*)d_ws) > ws_size) return;

    hipMemsetAsync(counts, 0, (size_t)N * 4, stream);
    hipMemsetAsync(cursor, 0, (size_t)N * 4, stream);
    hipMemsetAsync(agg, 0, (size_t)N * 64 * 4, stream);

    build_edges_k<<<(E + TPB - 1) / TPB, TPB, 0, stream>>>(ea, eb, pb, Ea, Eb, NC, Na, srcO, dstO);
    count_k<<<(E + TPB - 1) / TPB, TPB, 0, stream>>>(srcO, counts, E);
    scan1_k<<<nPart, TPB, 0, stream>>>(counts, offs, parts, N);
    scan2_k<<<1, 64, 0, stream>>>(parts, nPart);
    scan3_k<<<(N + 1 + TPB - 1) / TPB, TPB, 0, stream>>>(offs, parts, N, E);
    fill_k<<<(E + TPB - 1) / TPB, TPB, 0, stream>>>(srcO, dstO, offs, cursor, srcS, dstS, eOrigS, E);

    // h0 (bf16, src-sorted) + scatter h_1 = h0 into agg
    h0s_k<<<(int)(((long long)E * 64 + TPB - 1) / TPB), TPB, 0, stream>>>(
        xa, xb, efa, efb, srcS, dstS, eOrigS, Ea, Eb, Na, E, W_in, b_in, h0s, agg);

    int nblk = (N + 63) / 64;
    int egrid = (int)(((long long)E * 8 + TPB - 1) / TPB);
    const uint4* h0s16 = (const uint4*)h0s;
    const uint4* aggW16 = (const uint4*)aggW;

    for (int t = 1; t <= 100; t++) {
        nodegemm_k<<<nblk, TPB, 0, stream>>>(agg, W_msg, b_msg, aggW, N);
        if (t < 100)
            edge_bf16_k<1><<<egrid, TPB, 0, stream>>>(h0s16, aggW16, srcS, dstS, eOrigS,
                                                      agg, nullptr, E, off);
        else
            edge_bf16_k<2><<<egrid, TPB, 0, stream>>>(h0s16, aggW16, srcS, dstS, eOrigS,
                                                      agg, hsave, E, off);
    }

    nodeh_k<<<(int)(((long long)N * 32 + TPB - 1) / TPB), TPB, 0, stream>>>(
        xa, xb, Na, N, agg, W_node, b_node, nodeh);
    mlp2_k<<<(NC + TM2 - 1) / TM2, TPB, 0, stream>>>(nodeh, hsave, pb, NC, Na,
                                                     W1, b1, W2, b2, W3, b3, W4, b4, W5, b5, W6, b6,
                                                     (float*)d_out);
}

// Round 5
// 10550.054 us; speedup vs baseline: 13.3908x; 13.3908x over previous
//
#include <hip/hip_runtime.h>
#include <hip/hip_bf16.h>

#define TPB 256

// ================= edge list construction (original order) =================
__global__ void build_edges_k(const int* __restrict__ ea, const int* __restrict__ eb,
                              const int* __restrict__ pb,
                              int Ea, int Eb, int NC, int Na,
                              int* __restrict__ src, int* __restrict__ dst) {
    int e = blockIdx.x * TPB + threadIdx.x;
    int E = Ea + Eb + 2 * NC;
    if (e >= E) return;
    int s, d;
    if (e < Ea) { s = ea[2*e]; d = ea[2*e+1]; }
    else if (e < Ea + Eb) { int i = e - Ea; s = eb[2*i] + Na; d = eb[2*i+1] + Na; }
    else if (e < Ea + Eb + NC) { int c = e - Ea - Eb; s = pb[c]; d = pb[NC + c] + Na; }
    else { int c = e - Ea - Eb - NC; s = pb[NC + c] + Na; d = pb[c]; }
    src[e] = s; dst[e] = d;
}

__global__ void count_k(const int* __restrict__ key, int* __restrict__ counts, int E) {
    int e = blockIdx.x * TPB + threadIdx.x;
    if (e < E) atomicAdd(&counts[key[e]], 1);
}

// ---- exclusive scan over counts[0..N-1] -> offs ----
__global__ void scan1_k(const int* __restrict__ counts, int* __restrict__ offs,
                        int* __restrict__ partials, int N) {
    __shared__ int sdata[TPB];
    int tid = threadIdx.x;
    int base = blockIdx.x * 1024;
    int v[4]; int s = 0;
    #pragma unroll
    for (int r = 0; r < 4; r++) {
        int idx = base + tid * 4 + r;
        v[r] = (idx < N) ? counts[idx] : 0;
        s += v[r];
    }
    sdata[tid] = s;
    __syncthreads();
    for (int o = 1; o < TPB; o <<= 1) {
        int t = (tid >= o) ? sdata[tid - o] : 0;
        __syncthreads();
        sdata[tid] += t;
        __syncthreads();
    }
    if (tid == TPB - 1) partials[blockIdx.x] = sdata[TPB - 1];
    int run = sdata[tid] - s;
    #pragma unroll
    for (int r = 0; r < 4; r++) {
        int idx = base + tid * 4 + r;
        if (idx < N) offs[idx] = run;
        run += v[r];
    }
}

__global__ void scan2_k(int* __restrict__ partials, int nPart) {
    if (blockIdx.x == 0 && threadIdx.x == 0) {
        int acc = 0;
        for (int i = 0; i < nPart; i++) { int t = partials[i]; partials[i] = acc; acc += t; }
    }
}

__global__ void scan3_k(int* __restrict__ offs, const int* __restrict__ partials, int N, int E) {
    int i = blockIdx.x * TPB + threadIdx.x;
    if (i < N) offs[i] += partials[i >> 10];
    else if (i == N) offs[N] = E;
}

// fill: edges sorted by DST (CSR). srcS/eOrigS in dst-sorted order.
__global__ void fill_k(const int* __restrict__ src, const int* __restrict__ dst,
                       const int* __restrict__ offs, int* __restrict__ cursor,
                       int* __restrict__ srcS, int* __restrict__ eOrigS, int E) {
    int e = blockIdx.x * TPB + threadIdx.x;
    if (e >= E) return;
    int d = dst[e];
    int p = offs[d] + atomicAdd(&cursor[d], 1);
    srcS[p] = src[e];
    eOrigS[p] = e;
}

// ================= h0 (bf16, dst-sorted order) =================
__global__ void h0s_k(const float* __restrict__ xa, const float* __restrict__ xb,
                      const float* __restrict__ efa, const float* __restrict__ efb,
                      const int* __restrict__ srcS, const int* __restrict__ eOrigS,
                      int Ea, int Eb, int Na, int E,
                      const float* __restrict__ W_in, const float* __restrict__ b_in,
                      __hip_bfloat16* __restrict__ h0s) {
    __shared__ float Wl[6 * 64];
    __shared__ float bl[64];
    for (int t = threadIdx.x; t < 6 * 64; t += TPB) Wl[t] = W_in[t];
    if (threadIdx.x < 64) bl[threadIdx.x] = b_in[threadIdx.x];
    __syncthreads();
    long long gid = (long long)blockIdx.x * TPB + threadIdx.x;
    if (gid >= (long long)E * 64) return;
    int k = (int)(gid >> 6), j = (int)(gid & 63);
    int e = eOrigS[k];
    int s = srcS[k];
    const float* xp = (s < Na) ? (xa + (size_t)s * 5) : (xb + (size_t)(s - Na) * 5);
    float efv = (e < Ea) ? efa[e] : ((e < Ea + Eb) ? efb[e - Ea] : 999.0f);
    float acc = bl[j];
    #pragma unroll
    for (int i = 0; i < 5; i++) acc += xp[i] * Wl[i * 64 + j];
    acc += efv * Wl[5 * 64 + j];
    acc = fmaxf(acc, 0.0f);
    h0s[(size_t)gid] = __float2bfloat16(acc);
}

// ================= wave-per-node CSR aggregation (no atomics) =================
// thread = (node n, channel j); one wave = one node (wave-uniform degree loop).
// MODE 0: agg[n] = segsum(h0)          (h_1 = h0)
// MODE 1: agg[n] = segsum(relu(h0 + aggW[src]))
// MODE 2: MODE 1 + save h rows for candidate edges (eOrig >= off)
template<int MODE>
__global__ __launch_bounds__(TPB) void aggregate_k(const __hip_bfloat16* __restrict__ h0s,
                                                   const __hip_bfloat16* __restrict__ aggW,
                                                   const int* __restrict__ srcS,
                                                   const int* __restrict__ eOrigS,
                                                   const int* __restrict__ offs,
                                                   float* __restrict__ agg,
                                                   float* __restrict__ hsave,
                                                   int N, int off) {
    int gid = blockIdx.x * TPB + threadIdx.x;   // N*64 = 9.6M, fits int
    if (gid >= N * 64) return;
    int n = gid >> 6, j = gid & 63;
    int beg = offs[n], end = offs[n + 1];
    float acc = 0.0f;
    for (int k = beg; k < end; k++) {
        float v = __bfloat162float(h0s[(size_t)k * 64 + j]);
        if (MODE >= 1) {
            int s = srcS[k];                    // wave-uniform scalar load
            v += __bfloat162float(aggW[(size_t)s * 64 + j]);
            v = fmaxf(v, 0.0f);
        }
        if (MODE == 2) {
            int eo = eOrigS[k];                 // wave-uniform
            if (eo >= off) hsave[(size_t)(eo - off) * 64 + j] = v;
        }
        acc += v;
    }
    agg[(size_t)gid] = acc;
}

// ================= per-node GEMM: aggW(bf16) = agg @ W_msg + b_msg =================
__global__ __launch_bounds__(TPB) void nodegemm_k(const float* __restrict__ agg,
                                                  const float* __restrict__ W_msg,
                                                  const float* __restrict__ b_msg,
                                                  __hip_bfloat16* __restrict__ aggW, int N) {
    __shared__ __align__(16) float Wl[64 * 64];
    __shared__ float bl[64];
    __shared__ __align__(16) float actL[64 * 64];
    int tid = threadIdx.x;
    for (int t = tid; t < 4096; t += TPB) Wl[t] = W_msg[t];
    if (tid < 64) bl[tid] = b_msg[tid];
    size_t base = (size_t)blockIdx.x * 4096;
    size_t lim = (size_t)N * 64;
    for (int t = tid; t < 4096; t += TPB) {
        size_t g = base + t;
        actL[t] = (g < lim) ? agg[g] : 0.0f;
    }
    __syncthreads();
    int j = tid & 63;
    int n0 = (tid >> 6) * 16;
    float acc[16];
    #pragma unroll
    for (int k = 0; k < 16; k++) acc[k] = bl[j];
    const float4* act4 = (const float4*)actL;
    for (int i4 = 0; i4 < 16; i4++) {
        float w0 = Wl[(4 * i4 + 0) * 64 + j];
        float w1 = Wl[(4 * i4 + 1) * 64 + j];
        float w2 = Wl[(4 * i4 + 2) * 64 + j];
        float w3 = Wl[(4 * i4 + 3) * 64 + j];
        #pragma unroll
        for (int k = 0; k < 16; k++) {
            float4 a = act4[(n0 + k) * 16 + i4];
            acc[k] += a.x * w0 + a.y * w1 + a.z * w2 + a.w * w3;
        }
    }
    #pragma unroll
    for (int k = 0; k < 16; k++) {
        size_t g2 = base + (size_t)(n0 + k) * 64 + j;
        if (g2 < lim) aggW[g2] = __float2bfloat16(acc[k]);
    }
}

// ================= node_h = relu([x, agg] @ W_node + b_node) =================
__global__ void nodeh_k(const float* __restrict__ xa, const float* __restrict__ xb,
                        int Na, int N,
                        const float* __restrict__ agg,
                        const float* __restrict__ W_node, const float* __restrict__ b_node,
                        float* __restrict__ node_h) {
    __shared__ float Wl[69 * 32];
    __shared__ float bl[32];
    for (int t = threadIdx.x; t < 69 * 32; t += TPB) Wl[t] = W_node[t];
    if (threadIdx.x < 32) bl[threadIdx.x] = b_node[threadIdx.x];
    __syncthreads();
    long long gid = (long long)blockIdx.x * TPB + threadIdx.x;
    if (gid >= (long long)N * 32) return;
    int n = (int)(gid >> 5), j = (int)(gid & 31);
    const float* xp = (n < Na) ? (xa + (size_t)n * 5) : (xb + (size_t)(n - Na) * 5);
    float acc = bl[j];
    #pragma unroll
    for (int i = 0; i < 5; i++) acc += xp[i] * Wl[i * 32 + j];
    const float4* a4 = (const float4*)(agg + (size_t)n * 64);
    #pragma unroll
    for (int i4 = 0; i4 < 16; i4++) {
        float4 a = a4[i4];
        acc += a.x * Wl[(5 + 4 * i4 + 0) * 32 + j];
        acc += a.y * Wl[(5 + 4 * i4 + 1) * 32 + j];
        acc += a.z * Wl[(5 + 4 * i4 + 2) * 32 + j];
        acc += a.w * Wl[(5 + 4 * i4 + 3) * 32 + j];
    }
    node_h[gid] = fmaxf(acc, 0.0f);
}

// ================= MLP head =================
#define TM2 32
#define MSTR 260

__device__ __forceinline__ void mlp_layer2(const float* __restrict__ W, const float* __restrict__ b,
                                           int in, int out, int lgout,
                                           const float* __restrict__ A, float* __restrict__ B) {
    int pairs = out * (TM2 / 8);
    const float4* a4b = (const float4*)A;
    for (int p = threadIdx.x; p < pairs; p += TPB) {
        int j = p & (out - 1);
        int r0 = (p >> lgout) * 8;
        float acc[8];
        float bj = b[j];
        #pragma unroll
        for (int r = 0; r < 8; r++) acc[r] = bj;
        for (int i4 = 0; i4 < (in >> 2); i4++) {
            int i = i4 * 4;
            float w0 = W[(i + 0) * out + j];
            float w1 = W[(i + 1) * out + j];
            float w2 = W[(i + 2) * out + j];
            float w3 = W[(i + 3) * out + j];
            #pragma unroll
            for (int r = 0; r < 8; r++) {
                float4 a = a4b[(r0 + r) * 65 + i4];
                acc[r] += a.x * w0 + a.y * w1 + a.z * w2 + a.w * w3;
            }
        }
        #pragma unroll
        for (int r = 0; r < 8; r++) B[(r0 + r) * MSTR + j] = fmaxf(acc[r], 0.0f);
    }
    __syncthreads();
}

__global__ __launch_bounds__(TPB) void mlp2_k(const float* __restrict__ node_h,
                                              const float* __restrict__ hsave,
                                              const int* __restrict__ pb, int NC, int Na,
                                              const float* __restrict__ W1, const float* __restrict__ b1,
                                              const float* __restrict__ W2, const float* __restrict__ b2,
                                              const float* __restrict__ W3, const float* __restrict__ b3,
                                              const float* __restrict__ W4, const float* __restrict__ b4,
                                              const float* __restrict__ W5, const float* __restrict__ b5,
                                              const float* __restrict__ W6, const float* __restrict__ b6,
                                              float* __restrict__ out) {
    __shared__ __align__(16) float A[TM2 * MSTR];
    __shared__ __align__(16) float B[TM2 * MSTR];
    int c0 = blockIdx.x * TM2;
    for (int idx = threadIdx.x; idx < TM2 * 128; idx += TPB) {
        int r = idx >> 7, col = idx & 127;
        int c = c0 + r;
        float v = 0.0f;
        if (c < NC) {
            if (col < 32) v = node_h[(size_t)pb[c] * 32 + col];
            else if (col < 64) v = node_h[(size_t)(Na + pb[NC + c]) * 32 + (col - 32)];
            else v = hsave[(size_t)c * 64 + (col - 64)] + hsave[(size_t)(NC + c) * 64 + (col - 64)];
        }
        A[r * MSTR + col] = v;
    }
    __syncthreads();
    mlp_layer2(W1, b1, 128, 128, 7, A, B);
    mlp_layer2(W2, b2, 128, 256, 8, B, A);
    mlp_layer2(W3, b3, 256, 256, 8, A, B);
    mlp_layer2(W4, b4, 256, 128, 7, B, A);
    mlp_layer2(W5, b5, 128, 64, 6, A, B);
    if (threadIdx.x < TM2) {
        int r = threadIdx.x, c = c0 + r;
        if (c < NC) {
            float z[4];
            #pragma unroll
            for (int k = 0; k < 4; k++) {
                float acc = b6[k];
                for (int i = 0; i < 64; i++) acc += B[r * MSTR + i] * W6[i * 4 + k];
                z[k] = acc;
            }
            float m = fmaxf(fmaxf(z[0], z[1]), fmaxf(z[2], z[3]));
            float e0 = expf(z[0] - m), e1 = expf(z[1] - m), e2 = expf(z[2] - m), e3 = expf(z[3] - m);
            float inv = 1.0f / (e0 + e1 + e2 + e3);
            int am = 0; float bm = z[0];
            if (z[1] > bm) { bm = z[1]; am = 1; }
            if (z[2] > bm) { bm = z[2]; am = 2; }
            if (z[3] > bm) { bm = z[3]; am = 3; }
            out[(size_t)c * 3 + 0] = (float)pb[c];
            out[(size_t)c * 3 + 1] = (float)pb[NC + c];
            out[(size_t)c * 3 + 2] = (float)am;
            float* po = out + (size_t)NC * 3 + (size_t)c * 4;
            po[0] = e0 * inv; po[1] = e1 * inv; po[2] = e2 * inv; po[3] = e3 * inv;
        }
    }
}

extern "C" void kernel_launch(void* const* d_in, const int* in_sizes, int n_in,
                              void* d_out, int out_size, void* d_ws, size_t ws_size,
                              hipStream_t stream) {
    const float* xa   = (const float*)d_in[0];
    const float* efa  = (const float*)d_in[1];
    const int*   ea   = (const int*)d_in[2];
    const float* xb   = (const float*)d_in[3];
    const float* efb  = (const float*)d_in[4];
    const int*   eb   = (const int*)d_in[5];
    const int*   pb   = (const int*)d_in[6];
    const float* W_in   = (const float*)d_in[7];
    const float* b_in   = (const float*)d_in[8];
    const float* W_msg  = (const float*)d_in[9];
    const float* b_msg  = (const float*)d_in[10];
    const float* W_node = (const float*)d_in[11];
    const float* b_node = (const float*)d_in[12];
    const float* W1 = (const float*)d_in[13]; const float* b1 = (const float*)d_in[14];
    const float* W2 = (const float*)d_in[15]; const float* b2 = (const float*)d_in[16];
    const float* W3 = (const float*)d_in[17]; const float* b3 = (const float*)d_in[18];
    const float* W4 = (const float*)d_in[19]; const float* b4 = (const float*)d_in[20];
    const float* W5 = (const float*)d_in[21]; const float* b5 = (const float*)d_in[22];
    const float* W6 = (const float*)d_in[23]; const float* b6 = (const float*)d_in[24];

    int Na = in_sizes[0] / 5;
    int Ea = in_sizes[2] / 2;
    int Nb = in_sizes[3] / 5;
    int Eb = in_sizes[5] / 2;
    int NC = in_sizes[6] / 2;
    int N = Na + Nb;
    int E = Ea + Eb + 2 * NC;
    int off = Ea + Eb;
    int nPart = (N + 1023) / 1024;

    char* p = (char*)d_ws;
    auto alloc = [&](size_t bytes) { char* r = p; p += (bytes + 255) & ~(size_t)255; return r; };
    int*   srcO   = (int*)alloc((size_t)E * 4);
    int*   dstO   = (int*)alloc((size_t)E * 4);
    int*   counts = (int*)alloc((size_t)N * 4);
    int*   offs   = (int*)alloc((size_t)(N + 1) * 4);
    int*   cursor = (int*)alloc((size_t)N * 4);
    int*   parts  = (int*)alloc((size_t)nPart * 4);
    int*   srcS   = (int*)alloc((size_t)E * 4);
    int*   eOrigS = (int*)alloc((size_t)E * 4);
    __hip_bfloat16* h0s  = (__hip_bfloat16*)alloc((size_t)E * 64 * 2);
    float* agg    = (float*)alloc((size_t)N * 64 * 4);
    __hip_bfloat16* aggW = (__hip_bfloat16*)alloc((size_t)N * 64 * 2);
    float* hsave  = (float*)alloc((size_t)2 * NC * 64 * 4);
    float* nodeh  = (float*)alloc((size_t)N * 32 * 4);
    if ((size_t)(p - (char*)d_ws) > ws_size) return;

    hipMemsetAsync(counts, 0, (size_t)N * 4, stream);
    hipMemsetAsync(cursor, 0, (size_t)N * 4, stream);

    build_edges_k<<<(E + TPB - 1) / TPB, TPB, 0, stream>>>(ea, eb, pb, Ea, Eb, NC, Na, srcO, dstO);
    count_k<<<(E + TPB - 1) / TPB, TPB, 0, stream>>>(dstO, counts, E);
    scan1_k<<<nPart, TPB, 0, stream>>>(counts, offs, parts, N);
    scan2_k<<<1, 64, 0, stream>>>(parts, nPart);
    scan3_k<<<(N + 1 + TPB - 1) / TPB, TPB, 0, stream>>>(offs, parts, N, E);
    fill_k<<<(E + TPB - 1) / TPB, TPB, 0, stream>>>(srcO, dstO, offs, cursor, srcS, eOrigS, E);

    h0s_k<<<(int)(((long long)E * 64 + TPB - 1) / TPB), TPB, 0, stream>>>(
        xa, xb, efa, efb, srcS, eOrigS, Ea, Eb, Na, E, W_in, b_in, h0s);

    int agrid = (N * 64 + TPB - 1) / TPB;
    int nblk = (N + 63) / 64;

    // agg = segsum(h_1), h_1 = h0
    aggregate_k<0><<<agrid, TPB, 0, stream>>>(h0s, nullptr, nullptr, nullptr, offs,
                                              agg, nullptr, N, off);
    for (int t = 1; t <= 100; t++) {
        nodegemm_k<<<nblk, TPB, 0, stream>>>(agg, W_msg, b_msg, aggW, N);
        if (t < 100)
            aggregate_k<1><<<agrid, TPB, 0, stream>>>(h0s, aggW, srcS, eOrigS, offs,
                                                      agg, nullptr, N, off);
        else
            aggregate_k<2><<<agrid, TPB, 0, stream>>>(h0s, aggW, srcS, eOrigS, offs,
                                                      agg, hsave, N, off);
    }

    nodeh_k<<<(int)(((long long)N * 32 + TPB - 1) / TPB), TPB, 0, stream>>>(
        xa, xb, Na, N, agg, W_node, b_node, nodeh);
    mlp2_k<<<(NC + TM2 - 1) / TM2, TPB, 0, stream>>>(nodeh, hsave, pb, NC, Na,
                                                     W1, b1, W2, b2, W3, b3, W4, b4, W5, b5, W6, b6,
                                                     (float*)d_out);
}

// Round 6
// 8673.768 us; speedup vs baseline: 16.2875x; 1.2163x over previous
//
#include <hip/hip_runtime.h>
#include <hip/hip_bf16.h>

#define TPB 256

// ================= edge list construction (original order) =================
__global__ void build_edges_k(const int* __restrict__ ea, const int* __restrict__ eb,
                              const int* __restrict__ pb,
                              int Ea, int Eb, int NC, int Na,
                              int* __restrict__ src, int* __restrict__ dst) {
    int e = blockIdx.x * TPB + threadIdx.x;
    int E = Ea + Eb + 2 * NC;
    if (e >= E) return;
    int s, d;
    if (e < Ea) { s = ea[2*e]; d = ea[2*e+1]; }
    else if (e < Ea + Eb) { int i = e - Ea; s = eb[2*i] + Na; d = eb[2*i+1] + Na; }
    else if (e < Ea + Eb + NC) { int c = e - Ea - Eb; s = pb[c]; d = pb[NC + c] + Na; }
    else { int c = e - Ea - Eb - NC; s = pb[NC + c] + Na; d = pb[c]; }
    src[e] = s; dst[e] = d;
}

__global__ void count_k(const int* __restrict__ key, int* __restrict__ counts, int E) {
    int e = blockIdx.x * TPB + threadIdx.x;
    if (e < E) atomicAdd(&counts[key[e]], 1);
}

// ---- exclusive scan over counts[0..N-1] -> offs ----
__global__ void scan1_k(const int* __restrict__ counts, int* __restrict__ offs,
                        int* __restrict__ partials, int N) {
    __shared__ int sdata[TPB];
    int tid = threadIdx.x;
    int base = blockIdx.x * 1024;
    int v[4]; int s = 0;
    #pragma unroll
    for (int r = 0; r < 4; r++) {
        int idx = base + tid * 4 + r;
        v[r] = (idx < N) ? counts[idx] : 0;
        s += v[r];
    }
    sdata[tid] = s;
    __syncthreads();
    for (int o = 1; o < TPB; o <<= 1) {
        int t = (tid >= o) ? sdata[tid - o] : 0;
        __syncthreads();
        sdata[tid] += t;
        __syncthreads();
    }
    if (tid == TPB - 1) partials[blockIdx.x] = sdata[TPB - 1];
    int run = sdata[tid] - s;
    #pragma unroll
    for (int r = 0; r < 4; r++) {
        int idx = base + tid * 4 + r;
        if (idx < N) offs[idx] = run;
        run += v[r];
    }
}

__global__ void scan2_k(int* __restrict__ partials, int nPart) {
    if (blockIdx.x == 0 && threadIdx.x == 0) {
        int acc = 0;
        for (int i = 0; i < nPart; i++) { int t = partials[i]; partials[i] = acc; acc += t; }
    }
}

__global__ void scan3_k(int* __restrict__ offs, const int* __restrict__ partials, int N, int E) {
    int i = blockIdx.x * TPB + threadIdx.x;
    if (i < N) offs[i] += partials[i >> 10];
    else if (i == N) offs[N] = E;
}

// fill: edges sorted by DST (CSR). srcS/eOrigS in dst-sorted order.
__global__ void fill_k(const int* __restrict__ src, const int* __restrict__ dst,
                       const int* __restrict__ offs, int* __restrict__ cursor,
                       int* __restrict__ srcS, int* __restrict__ eOrigS, int E) {
    int e = blockIdx.x * TPB + threadIdx.x;
    if (e >= E) return;
    int d = dst[e];
    int p = offs[d] + atomicAdd(&cursor[d], 1);
    srcS[p] = src[e];
    eOrigS[p] = e;
}

// ================= h0 (bf16, dst-sorted order) =================
__global__ void h0s_k(const float* __restrict__ xa, const float* __restrict__ xb,
                      const float* __restrict__ efa, const float* __restrict__ efb,
                      const int* __restrict__ srcS, const int* __restrict__ eOrigS,
                      int Ea, int Eb, int Na, int E,
                      const float* __restrict__ W_in, const float* __restrict__ b_in,
                      __hip_bfloat16* __restrict__ h0s) {
    __shared__ float Wl[6 * 64];
    __shared__ float bl[64];
    for (int t = threadIdx.x; t < 6 * 64; t += TPB) Wl[t] = W_in[t];
    if (threadIdx.x < 64) bl[threadIdx.x] = b_in[threadIdx.x];
    __syncthreads();
    long long gid = (long long)blockIdx.x * TPB + threadIdx.x;
    if (gid >= (long long)E * 64) return;
    int k = (int)(gid >> 6), j = (int)(gid & 63);
    int e = eOrigS[k];
    int s = srcS[k];
    const float* xp = (s < Na) ? (xa + (size_t)s * 5) : (xb + (size_t)(s - Na) * 5);
    float efv = (e < Ea) ? efa[e] : ((e < Ea + Eb) ? efb[e - Ea] : 999.0f);
    float acc = bl[j];
    #pragma unroll
    for (int i = 0; i < 5; i++) acc += xp[i] * Wl[i * 64 + j];
    acc += efv * Wl[5 * 64 + j];
    acc = fmaxf(acc, 0.0f);
    h0s[(size_t)gid] = __float2bfloat16(acc);
}

__device__ __forceinline__ unsigned pack_bf16x2_rne(float a, float b) {
    unsigned u0 = __float_as_uint(a);
    unsigned u1 = __float_as_uint(b);
    u0 = (u0 + 0x7fffu + ((u0 >> 16) & 1u)) >> 16;
    u1 = (u1 + 0x7fffu + ((u1 >> 16) & 1u)) & 0xffff0000u;
    return u1 | u0;
}

// ================= wave-per-node CSR aggregation (no atomics, 2 edges/iter) =================
// wave = one node. lane l: half = l>>5 processes edges k = beg+half, +2, ...
// lane channel-pair cl = l&31 -> channels (2cl, 2cl+1), packed bf16x2 loads.
// MODE 0: agg[n] = segsum(h0)
// MODE 1: agg[n] = segsum(relu(h0 + aggW[src]))
// MODE 2: MODE 1 + save h rows (f32) for candidate edges (eOrig >= off)
template<int MODE>
__global__ __launch_bounds__(TPB) void aggregate_k(const unsigned* __restrict__ h0u,
                                                   const unsigned* __restrict__ aWu,
                                                   const int* __restrict__ srcS,
                                                   const int* __restrict__ eOrigS,
                                                   const int* __restrict__ offs,
                                                   unsigned* __restrict__ aggB,
                                                   float* __restrict__ hsave,
                                                   int N, int off) {
    int n = (blockIdx.x * TPB + threadIdx.x) >> 6;   // global wave id = node
    if (n >= N) return;
    int lane = threadIdx.x & 63;
    int half = lane >> 5, cl = lane & 31;
    int beg = offs[n], end = offs[n + 1];
    float a0 = 0.f, a1 = 0.f;
    for (int k = beg + half; k < end; k += 2) {
        unsigned hv = h0u[(size_t)k * 32 + cl];
        float v0 = __uint_as_float(hv << 16);
        float v1 = __uint_as_float(hv & 0xffff0000u);
        if (MODE >= 1) {
            int s = srcS[k];
            unsigned wv = aWu[(size_t)s * 32 + cl];
            v0 = fmaxf(v0 + __uint_as_float(wv << 16), 0.f);
            v1 = fmaxf(v1 + __uint_as_float(wv & 0xffff0000u), 0.f);
        }
        if (MODE == 2) {
            int eo = eOrigS[k];
            if (eo >= off) {
                float2 hw; hw.x = v0; hw.y = v1;
                *(float2*)(hsave + (size_t)(eo - off) * 64 + 2 * cl) = hw;
            }
        }
        a0 += v0; a1 += v1;
    }
    a0 += __shfl_xor(a0, 32, 64);
    a1 += __shfl_xor(a1, 32, 64);
    if (half == 0) aggB[(size_t)n * 32 + cl] = pack_bf16x2_rne(a0, a1);
}

// ================= per-node GEMM: aggW(bf16) = agg(bf16) @ W_msg + b_msg =================
__global__ __launch_bounds__(TPB) void nodegemm_k(const unsigned* __restrict__ aggB,
                                                  const float* __restrict__ W_msg,
                                                  const float* __restrict__ b_msg,
                                                  __hip_bfloat16* __restrict__ aggW, int N) {
    __shared__ __align__(16) float Wl[64 * 64];
    __shared__ float bl[64];
    __shared__ __align__(16) float actL[64 * 64];
    int tid = threadIdx.x;
    for (int t = tid; t < 4096; t += TPB) Wl[t] = W_msg[t];
    if (tid < 64) bl[tid] = b_msg[tid];
    size_t base32 = (size_t)blockIdx.x * 2048;
    size_t lim32 = (size_t)N * 32;
    for (int t = tid; t < 2048; t += TPB) {
        size_t g = base32 + t;
        unsigned u = (g < lim32) ? aggB[g] : 0u;
        actL[2 * t]     = __uint_as_float(u << 16);
        actL[2 * t + 1] = __uint_as_float(u & 0xffff0000u);
    }
    __syncthreads();
    int j = tid & 63;
    int n0 = (tid >> 6) * 16;
    float acc[16];
    #pragma unroll
    for (int k = 0; k < 16; k++) acc[k] = bl[j];
    const float4* act4 = (const float4*)actL;
    for (int i4 = 0; i4 < 16; i4++) {
        float w0 = Wl[(4 * i4 + 0) * 64 + j];
        float w1 = Wl[(4 * i4 + 1) * 64 + j];
        float w2 = Wl[(4 * i4 + 2) * 64 + j];
        float w3 = Wl[(4 * i4 + 3) * 64 + j];
        #pragma unroll
        for (int k = 0; k < 16; k++) {
            float4 a = act4[(n0 + k) * 16 + i4];
            acc[k] += a.x * w0 + a.y * w1 + a.z * w2 + a.w * w3;
        }
    }
    size_t baseN = (size_t)blockIdx.x * 4096;
    size_t lim = (size_t)N * 64;
    #pragma unroll
    for (int k = 0; k < 16; k++) {
        size_t g2 = baseN + (size_t)(n0 + k) * 64 + j;
        if (g2 < lim) aggW[g2] = __float2bfloat16(acc[k]);
    }
}

// ================= node_h = relu([x, agg] @ W_node + b_node) =================
__global__ void nodeh_k(const float* __restrict__ xa, const float* __restrict__ xb,
                        int Na, int N,
                        const unsigned* __restrict__ aggB,
                        const float* __restrict__ W_node, const float* __restrict__ b_node,
                        float* __restrict__ node_h) {
    __shared__ float Wl[69 * 32];
    __shared__ float bl[32];
    for (int t = threadIdx.x; t < 69 * 32; t += TPB) Wl[t] = W_node[t];
    if (threadIdx.x < 32) bl[threadIdx.x] = b_node[threadIdx.x];
    __syncthreads();
    long long gid = (long long)blockIdx.x * TPB + threadIdx.x;
    if (gid >= (long long)N * 32) return;
    int n = (int)(gid >> 5), j = (int)(gid & 31);
    const float* xp = (n < Na) ? (xa + (size_t)n * 5) : (xb + (size_t)(n - Na) * 5);
    float acc = bl[j];
    #pragma unroll
    for (int i = 0; i < 5; i++) acc += xp[i] * Wl[i * 32 + j];
    const unsigned* ar = aggB + (size_t)n * 32;
    #pragma unroll
    for (int i2 = 0; i2 < 32; i2++) {
        unsigned u = ar[i2];
        acc += __uint_as_float(u << 16)        * Wl[(5 + 2 * i2)     * 32 + j];
        acc += __uint_as_float(u & 0xffff0000u) * Wl[(5 + 2 * i2 + 1) * 32 + j];
    }
    node_h[gid] = fmaxf(acc, 0.0f);
}

// ================= MLP head =================
#define TM2 32
#define MSTR 260

__device__ __forceinline__ void mlp_layer2(const float* __restrict__ W, const float* __restrict__ b,
                                           int in, int out, int lgout,
                                           const float* __restrict__ A, float* __restrict__ B) {
    int pairs = out * (TM2 / 8);
    const float4* a4b = (const float4*)A;
    for (int p = threadIdx.x; p < pairs; p += TPB) {
        int j = p & (out - 1);
        int r0 = (p >> lgout) * 8;
        float acc[8];
        float bj = b[j];
        #pragma unroll
        for (int r = 0; r < 8; r++) acc[r] = bj;
        for (int i4 = 0; i4 < (in >> 2); i4++) {
            int i = i4 * 4;
            float w0 = W[(i + 0) * out + j];
            float w1 = W[(i + 1) * out + j];
            float w2 = W[(i + 2) * out + j];
            float w3 = W[(i + 3) * out + j];
            #pragma unroll
            for (int r = 0; r < 8; r++) {
                float4 a = a4b[(r0 + r) * 65 + i4];
                acc[r] += a.x * w0 + a.y * w1 + a.z * w2 + a.w * w3;
            }
        }
        #pragma unroll
        for (int r = 0; r < 8; r++) B[(r0 + r) * MSTR + j] = fmaxf(acc[r], 0.0f);
    }
    __syncthreads();
}

__global__ __launch_bounds__(TPB) void mlp2_k(const float* __restrict__ node_h,
                                              const float* __restrict__ hsave,
                                              const int* __restrict__ pb, int NC, int Na,
                                              const float* __restrict__ W1, const float* __restrict__ b1,
                                              const float* __restrict__ W2, const float* __restrict__ b2,
                                              const float* __restrict__ W3, const float* __restrict__ b3,
                                              const float* __restrict__ W4, const float* __restrict__ b4,
                                              const float* __restrict__ W5, const float* __restrict__ b5,
                                              const float* __restrict__ W6, const float* __restrict__ b6,
                                              float* __restrict__ out) {
    __shared__ __align__(16) float A[TM2 * MSTR];
    __shared__ __align__(16) float B[TM2 * MSTR];
    int c0 = blockIdx.x * TM2;
    for (int idx = threadIdx.x; idx < TM2 * 128; idx += TPB) {
        int r = idx >> 7, col = idx & 127;
        int c = c0 + r;
        float v = 0.0f;
        if (c < NC) {
            if (col < 32) v = node_h[(size_t)pb[c] * 32 + col];
            else if (col < 64) v = node_h[(size_t)(Na + pb[NC + c]) * 32 + (col - 32)];
            else v = hsave[(size_t)c * 64 + (col - 64)] + hsave[(size_t)(NC + c) * 64 + (col - 64)];
        }
        A[r * MSTR + col] = v;
    }
    __syncthreads();
    mlp_layer2(W1, b1, 128, 128, 7, A, B);
    mlp_layer2(W2, b2, 128, 256, 8, B, A);
    mlp_layer2(W3, b3, 256, 256, 8, A, B);
    mlp_layer2(W4, b4, 256, 128, 7, B, A);
    mlp_layer2(W5, b5, 128, 64, 6, A, B);
    if (threadIdx.x < TM2) {
        int r = threadIdx.x, c = c0 + r;
        if (c < NC) {
            float z[4];
            #pragma unroll
            for (int k = 0; k < 4; k++) {
                float acc = b6[k];
                for (int i = 0; i < 64; i++) acc += B[r * MSTR + i] * W6[i * 4 + k];
                z[k] = acc;
            }
            float m = fmaxf(fmaxf(z[0], z[1]), fmaxf(z[2], z[3]));
            float e0 = expf(z[0] - m), e1 = expf(z[1] - m), e2 = expf(z[2] - m), e3 = expf(z[3] - m);
            float inv = 1.0f / (e0 + e1 + e2 + e3);
            int am = 0; float bm = z[0];
            if (z[1] > bm) { bm = z[1]; am = 1; }
            if (z[2] > bm) { bm = z[2]; am = 2; }
            if (z[3] > bm) { bm = z[3]; am = 3; }
            out[(size_t)c * 3 + 0] = (float)pb[c];
            out[(size_t)c * 3 + 1] = (float)pb[NC + c];
            out[(size_t)c * 3 + 2] = (float)am;
            float* po = out + (size_t)NC * 3 + (size_t)c * 4;
            po[0] = e0 * inv; po[1] = e1 * inv; po[2] = e2 * inv; po[3] = e3 * inv;
        }
    }
}

extern "C" void kernel_launch(void* const* d_in, const int* in_sizes, int n_in,
                              void* d_out, int out_size, void* d_ws, size_t ws_size,
                              hipStream_t stream) {
    const float* xa   = (const float*)d_in[0];
    const float* efa  = (const float*)d_in[1];
    const int*   ea   = (const int*)d_in[2];
    const float* xb   = (const float*)d_in[3];
    const float* efb  = (const float*)d_in[4];
    const int*   eb   = (const int*)d_in[5];
    const int*   pb   = (const int*)d_in[6];
    const float* W_in   = (const float*)d_in[7];
    const float* b_in   = (const float*)d_in[8];
    const float* W_msg  = (const float*)d_in[9];
    const float* b_msg  = (const float*)d_in[10];
    const float* W_node = (const float*)d_in[11];
    const float* b_node = (const float*)d_in[12];
    const float* W1 = (const float*)d_in[13]; const float* b1 = (const float*)d_in[14];
    const float* W2 = (const float*)d_in[15]; const float* b2 = (const float*)d_in[16];
    const float* W3 = (const float*)d_in[17]; const float* b3 = (const float*)d_in[18];
    const float* W4 = (const float*)d_in[19]; const float* b4 = (const float*)d_in[20];
    const float* W5 = (const float*)d_in[21]; const float* b5 = (const float*)d_in[22];
    const float* W6 = (const float*)d_in[23]; const float* b6 = (const float*)d_in[24];

    int Na = in_sizes[0] / 5;
    int Ea = in_sizes[2] / 2;
    int Nb = in_sizes[3] / 5;
    int Eb = in_sizes[5] / 2;
    int NC = in_sizes[6] / 2;
    int N = Na + Nb;
    int E = Ea + Eb + 2 * NC;
    int off = Ea + Eb;
    int nPart = (N + 1023) / 1024;

    char* p = (char*)d_ws;
    auto alloc = [&](size_t bytes) { char* r = p; p += (bytes + 255) & ~(size_t)255; return r; };
    int*   srcO   = (int*)alloc((size_t)E * 4);
    int*   dstO   = (int*)alloc((size_t)E * 4);
    int*   counts = (int*)alloc((size_t)N * 4);
    int*   offs   = (int*)alloc((size_t)(N + 1) * 4);
    int*   cursor = (int*)alloc((size_t)N * 4);
    int*   parts  = (int*)alloc((size_t)nPart * 4);
    int*   srcS   = (int*)alloc((size_t)E * 4);
    int*   eOrigS = (int*)alloc((size_t)E * 4);
    __hip_bfloat16* h0s  = (__hip_bfloat16*)alloc((size_t)E * 64 * 2);
    unsigned* aggB = (unsigned*)alloc((size_t)N * 32 * 4);   // bf16x2 packed
    __hip_bfloat16* aggW = (__hip_bfloat16*)alloc((size_t)N * 64 * 2);
    float* hsave  = (float*)alloc((size_t)2 * NC * 64 * 4);
    float* nodeh  = (float*)alloc((size_t)N * 32 * 4);
    if ((size_t)(p - (char*)d_ws) > ws_size) return;

    hipMemsetAsync(counts, 0, (size_t)N * 4, stream);
    hipMemsetAsync(cursor, 0, (size_t)N * 4, stream);

    build_edges_k<<<(E + TPB - 1) / TPB, TPB, 0, stream>>>(ea, eb, pb, Ea, Eb, NC, Na, srcO, dstO);
    count_k<<<(E + TPB - 1) / TPB, TPB, 0, stream>>>(dstO, counts, E);
    scan1_k<<<nPart, TPB, 0, stream>>>(counts, offs, parts, N);
    scan2_k<<<1, 64, 0, stream>>>(parts, nPart);
    scan3_k<<<(N + 1 + TPB - 1) / TPB, TPB, 0, stream>>>(offs, parts, N, E);
    fill_k<<<(E + TPB - 1) / TPB, TPB, 0, stream>>>(srcO, dstO, offs, cursor, srcS, eOrigS, E);

    h0s_k<<<(int)(((long long)E * 64 + TPB - 1) / TPB), TPB, 0, stream>>>(
        xa, xb, efa, efb, srcS, eOrigS, Ea, Eb, Na, E, W_in, b_in, h0s);

    int agrid = (N * 64 + TPB - 1) / TPB;   // 4 waves/block, wave = node
    int nblk = (N + 63) / 64;
    const unsigned* h0u = (const unsigned*)h0s;
    const unsigned* aWu = (const unsigned*)aggW;

    aggregate_k<0><<<agrid, TPB, 0, stream>>>(h0u, nullptr, nullptr, nullptr, offs,
                                              aggB, nullptr, N, off);
    for (int t = 1; t <= 100; t++) {
        nodegemm_k<<<nblk, TPB, 0, stream>>>(aggB, W_msg, b_msg, aggW, N);
        if (t < 100)
            aggregate_k<1><<<agrid, TPB, 0, stream>>>(h0u, aWu, srcS, eOrigS, offs,
                                                      aggB, nullptr, N, off);
        else
            aggregate_k<2><<<agrid, TPB, 0, stream>>>(h0u, aWu, srcS, eOrigS, offs,
                                                      aggB, hsave, N, off);
    }

    nodeh_k<<<(int)(((long long)N * 32 + TPB - 1) / TPB), TPB, 0, stream>>>(
        xa, xb, Na, N, aggB, W_node, b_node, nodeh);
    mlp2_k<<<(NC + TM2 - 1) / TM2, TPB, 0, stream>>>(nodeh, hsave, pb, NC, Na,
                                                     W1, b1, W2, b2, W3, b3, W4, b4, W5, b5, W6, b6,
                                                     (float*)d_out);
}

// Round 7
// 6074.524 us; speedup vs baseline: 23.2568x; 1.4279x over previous
//
#include <hip/hip_runtime.h>
#include <hip/hip_bf16.h>

#define TPB 256

typedef __attribute__((ext_vector_type(8))) short short8v;
typedef __attribute__((ext_vector_type(4))) float f32x4;

// ================= edge list construction (original order) =================
__global__ void build_edges_k(const int* __restrict__ ea, const int* __restrict__ eb,
                              const int* __restrict__ pb,
                              int Ea, int Eb, int NC, int Na,
                              int* __restrict__ src, int* __restrict__ dst) {
    int e = blockIdx.x * TPB + threadIdx.x;
    int E = Ea + Eb + 2 * NC;
    if (e >= E) return;
    int s, d;
    if (e < Ea) { s = ea[2*e]; d = ea[2*e+1]; }
    else if (e < Ea + Eb) { int i = e - Ea; s = eb[2*i] + Na; d = eb[2*i+1] + Na; }
    else if (e < Ea + Eb + NC) { int c = e - Ea - Eb; s = pb[c]; d = pb[NC + c] + Na; }
    else { int c = e - Ea - Eb - NC; s = pb[NC + c] + Na; d = pb[c]; }
    src[e] = s; dst[e] = d;
}

__global__ void count_k(const int* __restrict__ key, int* __restrict__ counts, int E) {
    int e = blockIdx.x * TPB + threadIdx.x;
    if (e < E) atomicAdd(&counts[key[e]], 1);
}

__global__ void scan1_k(const int* __restrict__ counts, int* __restrict__ offs,
                        int* __restrict__ partials, int N) {
    __shared__ int sdata[TPB];
    int tid = threadIdx.x;
    int base = blockIdx.x * 1024;
    int v[4]; int s = 0;
    #pragma unroll
    for (int r = 0; r < 4; r++) {
        int idx = base + tid * 4 + r;
        v[r] = (idx < N) ? counts[idx] : 0;
        s += v[r];
    }
    sdata[tid] = s;
    __syncthreads();
    for (int o = 1; o < TPB; o <<= 1) {
        int t = (tid >= o) ? sdata[tid - o] : 0;
        __syncthreads();
        sdata[tid] += t;
        __syncthreads();
    }
    if (tid == TPB - 1) partials[blockIdx.x] = sdata[TPB - 1];
    int run = sdata[tid] - s;
    #pragma unroll
    for (int r = 0; r < 4; r++) {
        int idx = base + tid * 4 + r;
        if (idx < N) offs[idx] = run;
        run += v[r];
    }
}

__global__ void scan2_k(int* __restrict__ partials, int nPart) {
    if (blockIdx.x == 0 && threadIdx.x == 0) {
        int acc = 0;
        for (int i = 0; i < nPart; i++) { int t = partials[i]; partials[i] = acc; acc += t; }
    }
}

__global__ void scan3_k(int* __restrict__ offs, const int* __restrict__ partials, int N, int E) {
    int i = blockIdx.x * TPB + threadIdx.x;
    if (i < N) offs[i] += partials[i >> 10];
    else if (i == N) offs[N] = E;
}

__global__ void fill_k(const int* __restrict__ src, const int* __restrict__ dst,
                       const int* __restrict__ offs, int* __restrict__ cursor,
                       int* __restrict__ srcS, int* __restrict__ eOrigS, int E) {
    int e = blockIdx.x * TPB + threadIdx.x;
    if (e >= E) return;
    int d = dst[e];
    int p = offs[d] + atomicAdd(&cursor[d], 1);
    srcS[p] = src[e];
    eOrigS[p] = e;
}

// ================= ef in dst-sorted order =================
__global__ void efs_k(const int* __restrict__ eOrigS,
                      const float* __restrict__ efa, const float* __restrict__ efb,
                      int Ea, int Eb, int E, float* __restrict__ efS) {
    int k = blockIdx.x * TPB + threadIdx.x;
    if (k >= E) return;
    int e = eOrigS[k];
    efS[k] = (e < Ea) ? efa[e] : ((e < Ea + Eb) ? efb[e - Ea] : 999.0f);
}

__device__ __forceinline__ unsigned pack_bf16x2_rne(float a, float b) {
    unsigned u0 = __float_as_uint(a);
    unsigned u1 = __float_as_uint(b);
    u0 = (u0 + 0x7fffu + ((u0 >> 16) & 1u)) >> 16;
    u1 = (u1 + 0x7fffu + ((u1 >> 16) & 1u)) & 0xffff0000u;
    return u1 | u0;
}

// ================= xWb[n][c] = sum_i x[n][i]*W_in[i][c] + b_in[c]  (packed bf16x2) =================
__global__ void xwb_k(const float* __restrict__ xa, const float* __restrict__ xb,
                      int Na, int N,
                      const float* __restrict__ W_in, const float* __restrict__ b_in,
                      unsigned* __restrict__ xWb) {
    __shared__ float Wl[5 * 64];
    __shared__ float bl[64];
    for (int t = threadIdx.x; t < 5 * 64; t += TPB) Wl[t] = W_in[t];
    if (threadIdx.x < 64) bl[threadIdx.x] = b_in[threadIdx.x];
    __syncthreads();
    int gid = blockIdx.x * TPB + threadIdx.x;
    if (gid >= N * 32) return;
    int n = gid >> 5, cl = gid & 31;
    const float* xp = (n < Na) ? (xa + (size_t)n * 5) : (xb + (size_t)(n - Na) * 5);
    float c0 = bl[2 * cl], c1 = bl[2 * cl + 1];
    #pragma unroll
    for (int i = 0; i < 5; i++) {
        float xv = xp[i];
        c0 += xv * Wl[i * 64 + 2 * cl];
        c1 += xv * Wl[i * 64 + 2 * cl + 1];
    }
    xWb[(size_t)gid] = pack_bf16x2_rne(c0, c1);
}

// ================= W_msg -> MFMA B-fragment order (bf16), 8 frags x 64 lanes x 8 elems =================
// frag fi = ct*2+kt: B[k][col], k = kt*32 + (lane>>4)*8 + j, col = ct*16 + (lane&15)
__global__ void wfrag_k(const float* __restrict__ W_msg, __hip_bfloat16* __restrict__ Wf) {
    int t = blockIdx.x * TPB + threadIdx.x;
    if (t >= 4096) return;
    int j = t & 7, lane = (t >> 3) & 63, fi = t >> 9;
    int ct = fi >> 1, kt = fi & 1;
    int k = kt * 32 + (lane >> 4) * 8 + j;
    int col = ct * 16 + (lane & 15);
    Wf[t] = __float2bfloat16(W_msg[k * 64 + col]);
}

// ================= wave-per-node CSR aggregation, h0 recomputed on the fly =================
// MODE 0: agg[n] = segsum(relu(xWb[src]+ef*w5))
// MODE 1: agg[n] = segsum(relu(h0 + aggW[src]))
// MODE 2: MODE 1 + save h rows (f32) for candidate edges (eOrig >= off)
template<int MODE>
__global__ __launch_bounds__(TPB) void aggregate_k(const unsigned* __restrict__ xWb,
                                                   const float* __restrict__ efS,
                                                   const unsigned* __restrict__ aWu,
                                                   const int* __restrict__ srcS,
                                                   const int* __restrict__ eOrigS,
                                                   const int* __restrict__ offs,
                                                   const float* __restrict__ W_in5,
                                                   unsigned* __restrict__ aggB,
                                                   float* __restrict__ hsave,
                                                   int N, int off) {
    int n = (blockIdx.x * TPB + threadIdx.x) >> 6;
    if (n >= N) return;
    int lane = threadIdx.x & 63;
    int half = lane >> 5, cl = lane & 31;
    float w50 = W_in5[2 * cl], w51 = W_in5[2 * cl + 1];
    int beg = offs[n], end = offs[n + 1];
    float a0 = 0.f, a1 = 0.f;
    for (int k = beg + half; k < end; k += 2) {
        int s = srcS[k];
        float ef = efS[k];
        unsigned xv = xWb[(size_t)s * 32 + cl];
        float v0 = fmaxf(__uint_as_float(xv << 16) + ef * w50, 0.f);
        float v1 = fmaxf(__uint_as_float(xv & 0xffff0000u) + ef * w51, 0.f);
        if (MODE >= 1) {
            unsigned wv = aWu[(size_t)s * 32 + cl];
            v0 = fmaxf(v0 + __uint_as_float(wv << 16), 0.f);
            v1 = fmaxf(v1 + __uint_as_float(wv & 0xffff0000u), 0.f);
        }
        if (MODE == 2) {
            int eo = eOrigS[k];
            if (eo >= off) {
                float2 hw; hw.x = v0; hw.y = v1;
                *(float2*)(hsave + (size_t)(eo - off) * 64 + 2 * cl) = hw;
            }
        }
        a0 += v0; a1 += v1;
    }
    a0 += __shfl_xor(a0, 32, 64);
    a1 += __shfl_xor(a1, 32, 64);
    if (half == 0) aggB[(size_t)n * 32 + cl] = pack_bf16x2_rne(a0, a1);
}

// ================= MFMA node GEMM: aggW(bf16) = aggB(bf16) @ W_msg + b_msg =================
// block = 4 waves; wave = 16 nodes x 64 out-channels; W fragments held in VGPRs.
__global__ __launch_bounds__(TPB) void nodegemm_k(const unsigned* __restrict__ aggB,
                                                  const __hip_bfloat16* __restrict__ Wf,
                                                  const float* __restrict__ b_msg,
                                                  unsigned* __restrict__ aggWu, int N) {
    int lane = threadIdx.x & 63;
    int wv = threadIdx.x >> 6;
    int n0w = blockIdx.x * 64 + wv * 16;
    int arow = lane & 15;
    int kq = lane >> 4;

    short8v bfr[8];
    #pragma unroll
    for (int fi = 0; fi < 8; fi++)
        bfr[fi] = *reinterpret_cast<const short8v*>(Wf + ((size_t)(fi * 64 + lane)) * 8);

    f32x4 acc[4];
    #pragma unroll
    for (int ct = 0; ct < 4; ct++) {
        float bias = b_msg[ct * 16 + arow];
        acc[ct][0] = bias; acc[ct][1] = bias; acc[ct][2] = bias; acc[ct][3] = bias;
    }

    const short8v* pa0 = reinterpret_cast<const short8v*>(aggB + (size_t)(n0w + arow) * 32 + kq * 4);
    const short8v* pa1 = reinterpret_cast<const short8v*>(aggB + (size_t)(n0w + arow) * 32 + 16 + kq * 4);
    short8v a0 = *pa0;
    short8v a1 = *pa1;

    #pragma unroll
    for (int ct = 0; ct < 4; ct++) {
        acc[ct] = __builtin_amdgcn_mfma_f32_16x16x32_bf16(a0, bfr[2 * ct + 0], acc[ct], 0, 0, 0);
        acc[ct] = __builtin_amdgcn_mfma_f32_16x16x32_bf16(a1, bfr[2 * ct + 1], acc[ct], 0, 0, 0);
    }

    // C/D: col = lane&15, row = (lane>>4)*4 + reg. Pack channel pairs via lane^1.
    #pragma unroll
    for (int ct = 0; ct < 4; ct++) {
        #pragma unroll
        for (int r = 0; r < 4; r++) {
            float val = acc[ct][r];
            float partner = __shfl_xor(val, 1, 64);
            int n = n0w + kq * 4 + r;
            if (!(lane & 1) && n < N) {
                unsigned pk = pack_bf16x2_rne(val, partner);
                aggWu[(size_t)n * 32 + ct * 8 + (arow >> 1)] = pk;
            }
        }
    }
}

// ================= node_h = relu([x, agg] @ W_node + b_node) =================
__global__ void nodeh_k(const float* __restrict__ xa, const float* __restrict__ xb,
                        int Na, int N,
                        const unsigned* __restrict__ aggB,
                        const float* __restrict__ W_node, const float* __restrict__ b_node,
                        float* __restrict__ node_h) {
    __shared__ float Wl[69 * 32];
    __shared__ float bl[32];
    for (int t = threadIdx.x; t < 69 * 32; t += TPB) Wl[t] = W_node[t];
    if (threadIdx.x < 32) bl[threadIdx.x] = b_node[threadIdx.x];
    __syncthreads();
    long long gid = (long long)blockIdx.x * TPB + threadIdx.x;
    if (gid >= (long long)N * 32) return;
    int n = (int)(gid >> 5), j = (int)(gid & 31);
    const float* xp = (n < Na) ? (xa + (size_t)n * 5) : (xb + (size_t)(n - Na) * 5);
    float acc = bl[j];
    #pragma unroll
    for (int i = 0; i < 5; i++) acc += xp[i] * Wl[i * 32 + j];
    const unsigned* ar = aggB + (size_t)n * 32;
    #pragma unroll
    for (int i2 = 0; i2 < 32; i2++) {
        unsigned u = ar[i2];
        acc += __uint_as_float(u << 16)         * Wl[(5 + 2 * i2)     * 32 + j];
        acc += __uint_as_float(u & 0xffff0000u) * Wl[(5 + 2 * i2 + 1) * 32 + j];
    }
    node_h[gid] = fmaxf(acc, 0.0f);
}

// ================= MLP head =================
#define TM2 32
#define MSTR 260

__device__ __forceinline__ void mlp_layer2(const float* __restrict__ W, const float* __restrict__ b,
                                           int in, int out, int lgout,
                                           const float* __restrict__ A, float* __restrict__ B) {
    int pairs = out * (TM2 / 8);
    const float4* a4b = (const float4*)A;
    for (int p = threadIdx.x; p < pairs; p += TPB) {
        int j = p & (out - 1);
        int r0 = (p >> lgout) * 8;
        float acc[8];
        float bj = b[j];
        #pragma unroll
        for (int r = 0; r < 8; r++) acc[r] = bj;
        for (int i4 = 0; i4 < (in >> 2); i4++) {
            int i = i4 * 4;
            float w0 = W[(i + 0) * out + j];
            float w1 = W[(i + 1) * out + j];
            float w2 = W[(i + 2) * out + j];
            float w3 = W[(i + 3) * out + j];
            #pragma unroll
            for (int r = 0; r < 8; r++) {
                float4 a = a4b[(r0 + r) * 65 + i4];
                acc[r] += a.x * w0 + a.y * w1 + a.z * w2 + a.w * w3;
            }
        }
        #pragma unroll
        for (int r = 0; r < 8; r++) B[(r0 + r) * MSTR + j] = fmaxf(acc[r], 0.0f);
    }
    __syncthreads();
}

__global__ __launch_bounds__(TPB) void mlp2_k(const float* __restrict__ node_h,
                                              const float* __restrict__ hsave,
                                              const int* __restrict__ pb, int NC, int Na,
                                              const float* __restrict__ W1, const float* __restrict__ b1,
                                              const float* __restrict__ W2, const float* __restrict__ b2,
                                              const float* __restrict__ W3, const float* __restrict__ b3,
                                              const float* __restrict__ W4, const float* __restrict__ b4,
                                              const float* __restrict__ W5, const float* __restrict__ b5,
                                              const float* __restrict__ W6, const float* __restrict__ b6,
                                              float* __restrict__ out) {
    __shared__ __align__(16) float A[TM2 * MSTR];
    __shared__ __align__(16) float B[TM2 * MSTR];
    int c0 = blockIdx.x * TM2;
    for (int idx = threadIdx.x; idx < TM2 * 128; idx += TPB) {
        int r = idx >> 7, col = idx & 127;
        int c = c0 + r;
        float v = 0.0f;
        if (c < NC) {
            if (col < 32) v = node_h[(size_t)pb[c] * 32 + col];
            else if (col < 64) v = node_h[(size_t)(Na + pb[NC + c]) * 32 + (col - 32)];
            else v = hsave[(size_t)c * 64 + (col - 64)] + hsave[(size_t)(NC + c) * 64 + (col - 64)];
        }
        A[r * MSTR + col] = v;
    }
    __syncthreads();
    mlp_layer2(W1, b1, 128, 128, 7, A, B);
    mlp_layer2(W2, b2, 128, 256, 8, B, A);
    mlp_layer2(W3, b3, 256, 256, 8, A, B);
    mlp_layer2(W4, b4, 256, 128, 7, B, A);
    mlp_layer2(W5, b5, 128, 64, 6, A, B);
    if (threadIdx.x < TM2) {
        int r = threadIdx.x, c = c0 + r;
        if (c < NC) {
            float z[4];
            #pragma unroll
            for (int k = 0; k < 4; k++) {
                float acc = b6[k];
                for (int i = 0; i < 64; i++) acc += B[r * MSTR + i] * W6[i * 4 + k];
                z[k] = acc;
            }
            float m = fmaxf(fmaxf(z[0], z[1]), fmaxf(z[2], z[3]));
            float e0 = expf(z[0] - m), e1 = expf(z[1] - m), e2 = expf(z[2] - m), e3 = expf(z[3] - m);
            float inv = 1.0f / (e0 + e1 + e2 + e3);
            int am = 0; float bm = z[0];
            if (z[1] > bm) { bm = z[1]; am = 1; }
            if (z[2] > bm) { bm = z[2]; am = 2; }
            if (z[3] > bm) { bm = z[3]; am = 3; }
            out[(size_t)c * 3 + 0] = (float)pb[c];
            out[(size_t)c * 3 + 1] = (float)pb[NC + c];
            out[(size_t)c * 3 + 2] = (float)am;
            float* po = out + (size_t)NC * 3 + (size_t)c * 4;
            po[0] = e0 * inv; po[1] = e1 * inv; po[2] = e2 * inv; po[3] = e3 * inv;
        }
    }
}

extern "C" void kernel_launch(void* const* d_in, const int* in_sizes, int n_in,
                              void* d_out, int out_size, void* d_ws, size_t ws_size,
                              hipStream_t stream) {
    const float* xa   = (const float*)d_in[0];
    const float* efa  = (const float*)d_in[1];
    const int*   ea   = (const int*)d_in[2];
    const float* xb   = (const float*)d_in[3];
    const float* efb  = (const float*)d_in[4];
    const int*   eb   = (const int*)d_in[5];
    const int*   pb   = (const int*)d_in[6];
    const float* W_in   = (const float*)d_in[7];
    const float* b_in   = (const float*)d_in[8];
    const float* W_msg  = (const float*)d_in[9];
    const float* b_msg  = (const float*)d_in[10];
    const float* W_node = (const float*)d_in[11];
    const float* b_node = (const float*)d_in[12];
    const float* W1 = (const float*)d_in[13]; const float* b1 = (const float*)d_in[14];
    const float* W2 = (const float*)d_in[15]; const float* b2 = (const float*)d_in[16];
    const float* W3 = (const float*)d_in[17]; const float* b3 = (const float*)d_in[18];
    const float* W4 = (const float*)d_in[19]; const float* b4 = (const float*)d_in[20];
    const float* W5 = (const float*)d_in[21]; const float* b5 = (const float*)d_in[22];
    const float* W6 = (const float*)d_in[23]; const float* b6 = (const float*)d_in[24];

    int Na = in_sizes[0] / 5;
    int Ea = in_sizes[2] / 2;
    int Nb = in_sizes[3] / 5;
    int Eb = in_sizes[5] / 2;
    int NC = in_sizes[6] / 2;
    int N = Na + Nb;
    int Npad = (N + 63) & ~63;
    int E = Ea + Eb + 2 * NC;
    int off = Ea + Eb;
    int nPart = (N + 1023) / 1024;

    char* p = (char*)d_ws;
    auto alloc = [&](size_t bytes) { char* r = p; p += (bytes + 255) & ~(size_t)255; return r; };
    int*   srcO   = (int*)alloc((size_t)E * 4);
    int*   dstO   = (int*)alloc((size_t)E * 4);
    int*   counts = (int*)alloc((size_t)N * 4);
    int*   offs   = (int*)alloc((size_t)(N + 1) * 4);
    int*   cursor = (int*)alloc((size_t)N * 4);
    int*   parts  = (int*)alloc((size_t)nPart * 4);
    int*   srcS   = (int*)alloc((size_t)E * 4);
    int*   eOrigS = (int*)alloc((size_t)E * 4);
    float* efS    = (float*)alloc((size_t)E * 4);
    unsigned* xWb = (unsigned*)alloc((size_t)Npad * 32 * 4);
    unsigned* aggB = (unsigned*)alloc((size_t)Npad * 32 * 4);
    unsigned* aggWu = (unsigned*)alloc((size_t)Npad * 32 * 4);
    __hip_bfloat16* Wf = (__hip_bfloat16*)alloc(4096 * 2);
    float* hsave  = (float*)alloc((size_t)2 * NC * 64 * 4);
    float* nodeh  = (float*)alloc((size_t)N * 32 * 4);
    if ((size_t)(p - (char*)d_ws) > ws_size) return;

    hipMemsetAsync(counts, 0, (size_t)N * 4, stream);
    hipMemsetAsync(cursor, 0, (size_t)N * 4, stream);

    build_edges_k<<<(E + TPB - 1) / TPB, TPB, 0, stream>>>(ea, eb, pb, Ea, Eb, NC, Na, srcO, dstO);
    count_k<<<(E + TPB - 1) / TPB, TPB, 0, stream>>>(dstO, counts, E);
    scan1_k<<<nPart, TPB, 0, stream>>>(counts, offs, parts, N);
    scan2_k<<<1, 64, 0, stream>>>(parts, nPart);
    scan3_k<<<(N + 1 + TPB - 1) / TPB, TPB, 0, stream>>>(offs, parts, N, E);
    fill_k<<<(E + TPB - 1) / TPB, TPB, 0, stream>>>(srcO, dstO, offs, cursor, srcS, eOrigS, E);
    efs_k<<<(E + TPB - 1) / TPB, TPB, 0, stream>>>(eOrigS, efa, efb, Ea, Eb, E, efS);
    xwb_k<<<(N * 32 + TPB - 1) / TPB, TPB, 0, stream>>>(xa, xb, Na, N, W_in, b_in, xWb);
    wfrag_k<<<(4096 + TPB - 1) / TPB, TPB, 0, stream>>>(W_msg, Wf);

    const float* W_in5 = W_in + 5 * 64;
    int agrid = (N * 64 + TPB - 1) / TPB;   // 4 waves/block, wave = node
    int nblk = Npad / 64;

    aggregate_k<0><<<agrid, TPB, 0, stream>>>(xWb, efS, aggWu, srcS, eOrigS, offs, W_in5,
                                              aggB, nullptr, N, off);
    for (int t = 1; t <= 100; t++) {
        nodegemm_k<<<nblk, TPB, 0, stream>>>(aggB, Wf, b_msg, aggWu, N);
        if (t < 100)
            aggregate_k<1><<<agrid, TPB, 0, stream>>>(xWb, efS, aggWu, srcS, eOrigS, offs, W_in5,
                                                      aggB, nullptr, N, off);
        else
            aggregate_k<2><<<agrid, TPB, 0, stream>>>(xWb, efS, aggWu, srcS, eOrigS, offs, W_in5,
                                                      aggB, hsave, N, off);
    }

    nodeh_k<<<(int)(((long long)N * 32 + TPB - 1) / TPB), TPB, 0, stream>>>(
        xa, xb, Na, N, aggB, W_node, b_node, nodeh);
    mlp2_k<<<(NC + TM2 - 1) / TM2, TPB, 0, stream>>>(nodeh, hsave, pb, NC, Na,
                                                     W1, b1, W2, b2, W3, b3, W4, b4, W5, b5, W6, b6,
                                                     (float*)d_out);
}

// Round 8
// 5920.480 us; speedup vs baseline: 23.8619x; 1.0260x over previous
//
#include <hip/hip_runtime.h>
#include <hip/hip_bf16.h>

#define TPB 256

typedef __attribute__((ext_vector_type(8))) short short8v;
typedef __attribute__((ext_vector_type(4))) float f32x4;

// ================= edge list construction (original order) =================
__global__ void build_edges_k(const int* __restrict__ ea, const int* __restrict__ eb,
                              const int* __restrict__ pb,
                              int Ea, int Eb, int NC, int Na,
                              int* __restrict__ src, int* __restrict__ dst) {
    int e = blockIdx.x * TPB + threadIdx.x;
    int E = Ea + Eb + 2 * NC;
    if (e >= E) return;
    int s, d;
    if (e < Ea) { s = ea[2*e]; d = ea[2*e+1]; }
    else if (e < Ea + Eb) { int i = e - Ea; s = eb[2*i] + Na; d = eb[2*i+1] + Na; }
    else if (e < Ea + Eb + NC) { int c = e - Ea - Eb; s = pb[c]; d = pb[NC + c] + Na; }
    else { int c = e - Ea - Eb - NC; s = pb[NC + c] + Na; d = pb[c]; }
    src[e] = s; dst[e] = d;
}

__global__ void count_k(const int* __restrict__ key, int* __restrict__ counts, int E) {
    int e = blockIdx.x * TPB + threadIdx.x;
    if (e < E) atomicAdd(&counts[key[e]], 1);
}

__global__ void scan1_k(const int* __restrict__ counts, int* __restrict__ offs,
                        int* __restrict__ partials, int N) {
    __shared__ int sdata[TPB];
    int tid = threadIdx.x;
    int base = blockIdx.x * 1024;
    int v[4]; int s = 0;
    #pragma unroll
    for (int r = 0; r < 4; r++) {
        int idx = base + tid * 4 + r;
        v[r] = (idx < N) ? counts[idx] : 0;
        s += v[r];
    }
    sdata[tid] = s;
    __syncthreads();
    for (int o = 1; o < TPB; o <<= 1) {
        int t = (tid >= o) ? sdata[tid - o] : 0;
        __syncthreads();
        sdata[tid] += t;
        __syncthreads();
    }
    if (tid == TPB - 1) partials[blockIdx.x] = sdata[TPB - 1];
    int run = sdata[tid] - s;
    #pragma unroll
    for (int r = 0; r < 4; r++) {
        int idx = base + tid * 4 + r;
        if (idx < N) offs[idx] = run;
        run += v[r];
    }
}

__global__ void scan2_k(int* __restrict__ partials, int nPart) {
    if (blockIdx.x == 0 && threadIdx.x == 0) {
        int acc = 0;
        for (int i = 0; i < nPart; i++) { int t = partials[i]; partials[i] = acc; acc += t; }
    }
}

__global__ void scan3_k(int* __restrict__ offs, const int* __restrict__ partials, int N, int E) {
    int i = blockIdx.x * TPB + threadIdx.x;
    if (i < N) offs[i] += partials[i >> 10];
    else if (i == N) offs[N] = E;
}

__global__ void fill_k(const int* __restrict__ src, const int* __restrict__ dst,
                       const int* __restrict__ offs, int* __restrict__ cursor,
                       int* __restrict__ srcS, int* __restrict__ eOrigS, int E) {
    int e = blockIdx.x * TPB + threadIdx.x;
    if (e >= E) return;
    int d = dst[e];
    int p = offs[d] + atomicAdd(&cursor[d], 1);
    srcS[p] = src[e];
    eOrigS[p] = e;
}

// ================= edge metadata: srcEf[k] = {src, bits(ef)} =================
__global__ void meta_k(const int* __restrict__ srcS, const int* __restrict__ eOrigS,
                       const float* __restrict__ efa, const float* __restrict__ efb,
                       int Ea, int Eb, int E, int2* __restrict__ srcEf) {
    int k = blockIdx.x * TPB + threadIdx.x;
    if (k >= E) return;
    int e = eOrigS[k];
    float ef = (e < Ea) ? efa[e] : ((e < Ea + Eb) ? efb[e - Ea] : 999.0f);
    srcEf[k] = make_int2(srcS[k], __float_as_int(ef));
}

__device__ __forceinline__ unsigned pack_bf16x2_rne(float a, float b) {
    unsigned u0 = __float_as_uint(a);
    unsigned u1 = __float_as_uint(b);
    u0 = (u0 + 0x7fffu + ((u0 >> 16) & 1u)) >> 16;
    u1 = (u1 + 0x7fffu + ((u1 >> 16) & 1u)) & 0xffff0000u;
    return u1 | u0;
}

// ================= comb[n][c].xy = xWb channels 4c..4c+3 (packed bf16x2) =================
__global__ void xwb2_k(const float* __restrict__ xa, const float* __restrict__ xb,
                       int Na, int N,
                       const float* __restrict__ W_in, const float* __restrict__ b_in,
                       uint4* __restrict__ comb) {
    __shared__ float Wl[5 * 64];
    __shared__ float bl[64];
    for (int t = threadIdx.x; t < 5 * 64; t += TPB) Wl[t] = W_in[t];
    if (threadIdx.x < 64) bl[threadIdx.x] = b_in[threadIdx.x];
    __syncthreads();
    int gid = blockIdx.x * TPB + threadIdx.x;
    if (gid >= N * 16) return;
    int n = gid >> 4, c = gid & 15;
    const float* xp = (n < Na) ? (xa + (size_t)n * 5) : (xb + (size_t)(n - Na) * 5);
    float v[4];
    #pragma unroll
    for (int i = 0; i < 4; i++) {
        int ch = 4 * c + i;
        float acc = bl[ch];
        #pragma unroll
        for (int i5 = 0; i5 < 5; i5++) acc += xp[i5] * Wl[i5 * 64 + ch];
        v[i] = acc;
    }
    ((uint2*)comb)[(size_t)gid * 2] = make_uint2(pack_bf16x2_rne(v[0], v[1]),
                                                pack_bf16x2_rne(v[2], v[3]));
}

// ================= W_msg -> MFMA B-fragment order (bf16) =================
__global__ void wfrag_k(const float* __restrict__ W_msg, __hip_bfloat16* __restrict__ Wf) {
    int t = blockIdx.x * TPB + threadIdx.x;
    if (t >= 4096) return;
    int j = t & 7, lane = (t >> 3) & 63, fi = t >> 9;
    int ct = fi >> 1, kt = fi & 1;
    int k = kt * 32 + (lane >> 4) * 8 + j;
    int col = ct * 16 + (lane & 15);
    Wf[t] = __float2bfloat16(W_msg[k * 64 + col]);
}

// ================= wave-per-node CSR aggregation: one uint4 gather per edge-lane =================
// wave = node. lane: q = lane>>4 (edge slot), cq = lane&15 (4 channels 4cq..4cq+3).
// 4 edges per iteration; comb row carries BOTH xWb and aggW for the src node.
// MODE 0: agg[n] = segsum(relu(xWb+ef*w5));  MODE 1: segsum(relu(h0+aggW));  MODE 2: +hsave
template<int MODE>
__global__ __launch_bounds__(TPB) void aggregate_k(const uint4* __restrict__ comb,
                                                   const int2* __restrict__ srcEf,
                                                   const int* __restrict__ eOrigS,
                                                   const int* __restrict__ offs,
                                                   const float* __restrict__ W_in5,
                                                   uint2* __restrict__ aggB2,
                                                   float* __restrict__ hsave,
                                                   int N, int off) {
    int n = (blockIdx.x * TPB + threadIdx.x) >> 6;
    if (n >= N) return;
    int lane = threadIdx.x & 63;
    int q = lane >> 4, cq = lane & 15;
    float4 w5 = ((const float4*)W_in5)[cq];
    int beg = offs[n], end = offs[n + 1];
    float a0 = 0.f, a1 = 0.f, a2 = 0.f, a3 = 0.f;
    for (int k = beg + q; k < end; k += 4) {
        int2 se = srcEf[k];
        float ef = __int_as_float(se.y);
        uint4 cb = comb[(size_t)se.x * 16 + cq];
        float v0 = fmaxf(__uint_as_float(cb.x << 16)         + ef * w5.x, 0.f);
        float v1 = fmaxf(__uint_as_float(cb.x & 0xffff0000u) + ef * w5.y, 0.f);
        float v2 = fmaxf(__uint_as_float(cb.y << 16)         + ef * w5.z, 0.f);
        float v3 = fmaxf(__uint_as_float(cb.y & 0xffff0000u) + ef * w5.w, 0.f);
        if (MODE >= 1) {
            v0 = fmaxf(v0 + __uint_as_float(cb.z << 16),         0.f);
            v1 = fmaxf(v1 + __uint_as_float(cb.z & 0xffff0000u), 0.f);
            v2 = fmaxf(v2 + __uint_as_float(cb.w << 16),         0.f);
            v3 = fmaxf(v3 + __uint_as_float(cb.w & 0xffff0000u), 0.f);
        }
        if (MODE == 2) {
            int eo = eOrigS[k];
            if (eo >= off) {
                float4 hv; hv.x = v0; hv.y = v1; hv.z = v2; hv.w = v3;
                *(float4*)(hsave + (size_t)(eo - off) * 64 + 4 * cq) = hv;
            }
        }
        a0 += v0; a1 += v1; a2 += v2; a3 += v3;
    }
    a0 += __shfl_xor(a0, 16, 64); a0 += __shfl_xor(a0, 32, 64);
    a1 += __shfl_xor(a1, 16, 64); a1 += __shfl_xor(a1, 32, 64);
    a2 += __shfl_xor(a2, 16, 64); a2 += __shfl_xor(a2, 32, 64);
    a3 += __shfl_xor(a3, 16, 64); a3 += __shfl_xor(a3, 32, 64);
    if (q == 0)
        aggB2[(size_t)n * 16 + cq] = make_uint2(pack_bf16x2_rne(a0, a1),
                                                pack_bf16x2_rne(a2, a3));
}

// ================= MFMA node GEMM: comb.zw = aggB(bf16) @ W_msg + b_msg =================
__global__ __launch_bounds__(TPB) void nodegemm_k(const unsigned* __restrict__ aggB,
                                                  const __hip_bfloat16* __restrict__ Wf,
                                                  const float* __restrict__ b_msg,
                                                  uint4* __restrict__ comb, int N) {
    int lane = threadIdx.x & 63;
    int wv = threadIdx.x >> 6;
    int n0w = blockIdx.x * 64 + wv * 16;
    int arow = lane & 15;
    int kq = lane >> 4;

    short8v bfr[8];
    #pragma unroll
    for (int fi = 0; fi < 8; fi++)
        bfr[fi] = *reinterpret_cast<const short8v*>(Wf + ((size_t)(fi * 64 + lane)) * 8);

    f32x4 acc[4];
    #pragma unroll
    for (int ct = 0; ct < 4; ct++) {
        float bias = b_msg[ct * 16 + arow];
        acc[ct][0] = bias; acc[ct][1] = bias; acc[ct][2] = bias; acc[ct][3] = bias;
    }

    short8v a0 = *reinterpret_cast<const short8v*>(aggB + (size_t)(n0w + arow) * 32 + kq * 4);
    short8v a1 = *reinterpret_cast<const short8v*>(aggB + (size_t)(n0w + arow) * 32 + 16 + kq * 4);

    #pragma unroll
    for (int ct = 0; ct < 4; ct++) {
        acc[ct] = __builtin_amdgcn_mfma_f32_16x16x32_bf16(a0, bfr[2 * ct + 0], acc[ct], 0, 0, 0);
        acc[ct] = __builtin_amdgcn_mfma_f32_16x16x32_bf16(a1, bfr[2 * ct + 1], acc[ct], 0, 0, 0);
    }

    // C/D: col = lane&15, row = (lane>>4)*4 + reg.
    // lane with arow%4==0 assembles uint2 {ch..ch+1, ch+2..ch+3} and writes comb[n][c].zw
    #pragma unroll
    for (int ct = 0; ct < 4; ct++) {
        #pragma unroll
        for (int r = 0; r < 4; r++) {
            float val = acc[ct][r];
            float partner = __shfl_xor(val, 1, 64);
            unsigned pk0 = pack_bf16x2_rne(val, partner);
            unsigned pk1 = __shfl_xor(pk0, 2, 64);
            int n = n0w + kq * 4 + r;
            if (((lane & 3) == 0) && n < N) {
                int c = ct * 4 + (arow >> 2);
                ((uint2*)comb)[((size_t)n * 16 + c) * 2 + 1] = make_uint2(pk0, pk1);
            }
        }
    }
}

// ================= node_h = relu([x, agg] @ W_node + b_node) =================
__global__ void nodeh_k(const float* __restrict__ xa, const float* __restrict__ xb,
                        int Na, int N,
                        const unsigned* __restrict__ aggB,
                        const float* __restrict__ W_node, const float* __restrict__ b_node,
                        float* __restrict__ node_h) {
    __shared__ float Wl[69 * 32];
    __shared__ float bl[32];
    for (int t = threadIdx.x; t < 69 * 32; t += TPB) Wl[t] = W_node[t];
    if (threadIdx.x < 32) bl[threadIdx.x] = b_node[threadIdx.x];
    __syncthreads();
    long long gid = (long long)blockIdx.x * TPB + threadIdx.x;
    if (gid >= (long long)N * 32) return;
    int n = (int)(gid >> 5), j = (int)(gid & 31);
    const float* xp = (n < Na) ? (xa + (size_t)n * 5) : (xb + (size_t)(n - Na) * 5);
    float acc = bl[j];
    #pragma unroll
    for (int i = 0; i < 5; i++) acc += xp[i] * Wl[i * 32 + j];
    const unsigned* ar = aggB + (size_t)n * 32;
    #pragma unroll
    for (int i2 = 0; i2 < 32; i2++) {
        unsigned u = ar[i2];
        acc += __uint_as_float(u << 16)         * Wl[(5 + 2 * i2)     * 32 + j];
        acc += __uint_as_float(u & 0xffff0000u) * Wl[(5 + 2 * i2 + 1) * 32 + j];
    }
    node_h[gid] = fmaxf(acc, 0.0f);
}

// ================= MLP head =================
#define TM2 32
#define MSTR 260

__device__ __forceinline__ void mlp_layer2(const float* __restrict__ W, const float* __restrict__ b,
                                           int in, int out, int lgout,
                                           const float* __restrict__ A, float* __restrict__ B) {
    int pairs = out * (TM2 / 8);
    const float4* a4b = (const float4*)A;
    for (int p = threadIdx.x; p < pairs; p += TPB) {
        int j = p & (out - 1);
        int r0 = (p >> lgout) * 8;
        float acc[8];
        float bj = b[j];
        #pragma unroll
        for (int r = 0; r < 8; r++) acc[r] = bj;
        for (int i4 = 0; i4 < (in >> 2); i4++) {
            int i = i4 * 4;
            float w0 = W[(i + 0) * out + j];
            float w1 = W[(i + 1) * out + j];
            float w2 = W[(i + 2) * out + j];
            float w3 = W[(i + 3) * out + j];
            #pragma unroll
            for (int r = 0; r < 8; r++) {
                float4 a = a4b[(r0 + r) * 65 + i4];
                acc[r] += a.x * w0 + a.y * w1 + a.z * w2 + a.w * w3;
            }
        }
        #pragma unroll
        for (int r = 0; r < 8; r++) B[(r0 + r) * MSTR + j] = fmaxf(acc[r], 0.0f);
    }
    __syncthreads();
}

__global__ __launch_bounds__(TPB) void mlp2_k(const float* __restrict__ node_h,
                                              const float* __restrict__ hsave,
                                              const int* __restrict__ pb, int NC, int Na,
                                              const float* __restrict__ W1, const float* __restrict__ b1,
                                              const float* __restrict__ W2, const float* __restrict__ b2,
                                              const float* __restrict__ W3, const float* __restrict__ b3,
                                              const float* __restrict__ W4, const float* __restrict__ b4,
                                              const float* __restrict__ W5, const float* __restrict__ b5,
                                              const float* __restrict__ W6, const float* __restrict__ b6,
                                              float* __restrict__ out) {
    __shared__ __align__(16) float A[TM2 * MSTR];
    __shared__ __align__(16) float B[TM2 * MSTR];
    int c0 = blockIdx.x * TM2;
    for (int idx = threadIdx.x; idx < TM2 * 128; idx += TPB) {
        int r = idx >> 7, col = idx & 127;
        int c = c0 + r;
        float v = 0.0f;
        if (c < NC) {
            if (col < 32) v = node_h[(size_t)pb[c] * 32 + col];
            else if (col < 64) v = node_h[(size_t)(Na + pb[NC + c]) * 32 + (col - 32)];
            else v = hsave[(size_t)c * 64 + (col - 64)] + hsave[(size_t)(NC + c) * 64 + (col - 64)];
        }
        A[r * MSTR + col] = v;
    }
    __syncthreads();
    mlp_layer2(W1, b1, 128, 128, 7, A, B);
    mlp_layer2(W2, b2, 128, 256, 8, B, A);
    mlp_layer2(W3, b3, 256, 256, 8, A, B);
    mlp_layer2(W4, b4, 256, 128, 7, B, A);
    mlp_layer2(W5, b5, 128, 64, 6, A, B);
    if (threadIdx.x < TM2) {
        int r = threadIdx.x, c = c0 + r;
        if (c < NC) {
            float z[4];
            #pragma unroll
            for (int k = 0; k < 4; k++) {
                float acc = b6[k];
                for (int i = 0; i < 64; i++) acc += B[r * MSTR + i] * W6[i * 4 + k];
                z[k] = acc;
            }
            float m = fmaxf(fmaxf(z[0], z[1]), fmaxf(z[2], z[3]));
            float e0 = expf(z[0] - m), e1 = expf(z[1] - m), e2 = expf(z[2] - m), e3 = expf(z[3] - m);
            float inv = 1.0f / (e0 + e1 + e2 + e3);
            int am = 0; float bm = z[0];
            if (z[1] > bm) { bm = z[1]; am = 1; }
            if (z[2] > bm) { bm = z[2]; am = 2; }
            if (z[3] > bm) { bm = z[3]; am = 3; }
            out[(size_t)c * 3 + 0] = (float)pb[c];
            out[(size_t)c * 3 + 1] = (float)pb[NC + c];
            out[(size_t)c * 3 + 2] = (float)am;
            float* po = out + (size_t)NC * 3 + (size_t)c * 4;
            po[0] = e0 * inv; po[1] = e1 * inv; po[2] = e2 * inv; po[3] = e3 * inv;
        }
    }
}

extern "C" void kernel_launch(void* const* d_in, const int* in_sizes, int n_in,
                              void* d_out, int out_size, void* d_ws, size_t ws_size,
                              hipStream_t stream) {
    const float* xa   = (const float*)d_in[0];
    const float* efa  = (const float*)d_in[1];
    const int*   ea   = (const int*)d_in[2];
    const float* xb   = (const float*)d_in[3];
    const float* efb  = (const float*)d_in[4];
    const int*   eb   = (const int*)d_in[5];
    const int*   pb   = (const int*)d_in[6];
    const float* W_in   = (const float*)d_in[7];
    const float* b_in   = (const float*)d_in[8];
    const float* W_msg  = (const float*)d_in[9];
    const float* b_msg  = (const float*)d_in[10];
    const float* W_node = (const float*)d_in[11];
    const float* b_node = (const float*)d_in[12];
    const float* W1 = (const float*)d_in[13]; const float* b1 = (const float*)d_in[14];
    const float* W2 = (const float*)d_in[15]; const float* b2 = (const float*)d_in[16];
    const float* W3 = (const float*)d_in[17]; const float* b3 = (const float*)d_in[18];
    const float* W4 = (const float*)d_in[19]; const float* b4 = (const float*)d_in[20];
    const float* W5 = (const float*)d_in[21]; const float* b5 = (const float*)d_in[22];
    const float* W6 = (const float*)d_in[23]; const float* b6 = (const float*)d_in[24];

    int Na = in_sizes[0] / 5;
    int Ea = in_sizes[2] / 2;
    int Nb = in_sizes[3] / 5;
    int Eb = in_sizes[5] / 2;
    int NC = in_sizes[6] / 2;
    int N = Na + Nb;
    int Npad = (N + 63) & ~63;
    int E = Ea + Eb + 2 * NC;
    int off = Ea + Eb;
    int nPart = (N + 1023) / 1024;

    char* p = (char*)d_ws;
    auto alloc = [&](size_t bytes) { char* r = p; p += (bytes + 255) & ~(size_t)255; return r; };
    int*   srcO   = (int*)alloc((size_t)E * 4);
    int*   dstO   = (int*)alloc((size_t)E * 4);
    int*   counts = (int*)alloc((size_t)N * 4);
    int*   offs   = (int*)alloc((size_t)(N + 1) * 4);
    int*   cursor = (int*)alloc((size_t)N * 4);
    int*   parts  = (int*)alloc((size_t)nPart * 4);
    int*   srcS   = (int*)alloc((size_t)E * 4);
    int*   eOrigS = (int*)alloc((size_t)E * 4);
    int2*  srcEf  = (int2*)alloc((size_t)E * 8);
    uint4* comb   = (uint4*)alloc((size_t)Npad * 16 * 16);
    uint2* aggB2  = (uint2*)alloc((size_t)Npad * 16 * 8);
    __hip_bfloat16* Wf = (__hip_bfloat16*)alloc(4096 * 2);
    float* hsave  = (float*)alloc((size_t)2 * NC * 64 * 4);
    float* nodeh  = (float*)alloc((size_t)N * 32 * 4);
    if ((size_t)(p - (char*)d_ws) > ws_size) return;

    hipMemsetAsync(counts, 0, (size_t)N * 4, stream);
    hipMemsetAsync(cursor, 0, (size_t)N * 4, stream);

    build_edges_k<<<(E + TPB - 1) / TPB, TPB, 0, stream>>>(ea, eb, pb, Ea, Eb, NC, Na, srcO, dstO);
    count_k<<<(E + TPB - 1) / TPB, TPB, 0, stream>>>(dstO, counts, E);
    scan1_k<<<nPart, TPB, 0, stream>>>(counts, offs, parts, N);
    scan2_k<<<1, 64, 0, stream>>>(parts, nPart);
    scan3_k<<<(N + 1 + TPB - 1) / TPB, TPB, 0, stream>>>(offs, parts, N, E);
    fill_k<<<(E + TPB - 1) / TPB, TPB, 0, stream>>>(srcO, dstO, offs, cursor, srcS, eOrigS, E);
    meta_k<<<(E + TPB - 1) / TPB, TPB, 0, stream>>>(srcS, eOrigS, efa, efb, Ea, Eb, E, srcEf);
    xwb2_k<<<(N * 16 + TPB - 1) / TPB, TPB, 0, stream>>>(xa, xb, Na, N, W_in, b_in, comb);
    wfrag_k<<<(4096 + TPB - 1) / TPB, TPB, 0, stream>>>(W_msg, Wf);

    const float* W_in5 = W_in + 5 * 64;
    int agrid = (N * 64 + TPB - 1) / TPB;   // 4 waves/block, wave = node
    int nblk = Npad / 64;
    const unsigned* aggBu = (const unsigned*)aggB2;

    aggregate_k<0><<<agrid, TPB, 0, stream>>>(comb, srcEf, eOrigS, offs, W_in5,
                                              aggB2, nullptr, N, off);
    for (int t = 1; t <= 100; t++) {
        nodegemm_k<<<nblk, TPB, 0, stream>>>(aggBu, Wf, b_msg, comb, N);
        if (t < 100)
            aggregate_k<1><<<agrid, TPB, 0, stream>>>(comb, srcEf, eOrigS, offs, W_in5,
                                                      aggB2, nullptr, N, off);
        else
            aggregate_k<2><<<agrid, TPB, 0, stream>>>(comb, srcEf, eOrigS, offs, W_in5,
                                                      aggB2, hsave, N, off);
    }

    nodeh_k<<<(int)(((long long)N * 32 + TPB - 1) / TPB), TPB, 0, stream>>>(
        xa, xb, Na, N, aggBu, W_node, b_node, nodeh);
    mlp2_k<<<(NC + TM2 - 1) / TM2, TPB, 0, stream>>>(nodeh, hsave, pb, NC, Na,
                                                     W1, b1, W2, b2, W3, b3, W4, b4, W5, b5, W6, b6,
                                                     (float*)d_out);
}

// Round 9
// 5881.077 us; speedup vs baseline: 24.0218x; 1.0067x over previous
//
#include <hip/hip_runtime.h>
#include <hip/hip_bf16.h>

#define TPB 256

typedef __attribute__((ext_vector_type(8))) short short8v;
typedef __attribute__((ext_vector_type(4))) float f32x4;

// ================= fp8 e4m3 helpers (self-consistent manual roundtrip) =================
__device__ __forceinline__ unsigned enc_fp8(float v) {
    unsigned u = __float_as_uint(v);
    unsigned s = (u >> 24) & 0x80u;
    unsigned mag = u & 0x7fffffffu;
    mag += 0x7ffffu + ((mag >> 20) & 1u);          // RNE to 3 mantissa bits
    if (mag < 0x3C800000u) return s;               // flush < 2^-6 to zero
    if (mag > 0x43E00000u) mag = 0x43E00000u;      // clamp to 448
    return s | (((mag >> 23) - 120u) << 3) | ((mag >> 20) & 7u);
}
__device__ __forceinline__ float dec_fp8(unsigned b) {
    unsigned s = (b & 0x80u) << 24;
    unsigned e = (b >> 3) & 15u;
    unsigned m = b & 7u;
    unsigned bits = s | ((e + 120u) << 23) | (m << 20);
    return (e == 0) ? __uint_as_float(s) : __uint_as_float(bits);
}

__device__ __forceinline__ unsigned pack_bf16x2_rne(float a, float b) {
    unsigned u0 = __float_as_uint(a);
    unsigned u1 = __float_as_uint(b);
    u0 = (u0 + 0x7fffu + ((u0 >> 16) & 1u)) >> 16;
    u1 = (u1 + 0x7fffu + ((u1 >> 16) & 1u)) & 0xffff0000u;
    return u1 | u0;
}

// ================= edge list construction (original order) =================
__global__ void build_edges_k(const int* __restrict__ ea, const int* __restrict__ eb,
                              const int* __restrict__ pb,
                              int Ea, int Eb, int NC, int Na,
                              int* __restrict__ src, int* __restrict__ dst) {
    int e = blockIdx.x * TPB + threadIdx.x;
    int E = Ea + Eb + 2 * NC;
    if (e >= E) return;
    int s, d;
    if (e < Ea) { s = ea[2*e]; d = ea[2*e+1]; }
    else if (e < Ea + Eb) { int i = e - Ea; s = eb[2*i] + Na; d = eb[2*i+1] + Na; }
    else if (e < Ea + Eb + NC) { int c = e - Ea - Eb; s = pb[c]; d = pb[NC + c] + Na; }
    else { int c = e - Ea - Eb - NC; s = pb[NC + c] + Na; d = pb[c]; }
    src[e] = s; dst[e] = d;
}

__global__ void count_k(const int* __restrict__ key, int* __restrict__ counts, int E) {
    int e = blockIdx.x * TPB + threadIdx.x;
    if (e < E) atomicAdd(&counts[key[e]], 1);
}

__global__ void scan1_k(const int* __restrict__ counts, int* __restrict__ offs,
                        int* __restrict__ partials, int N) {
    __shared__ int sdata[TPB];
    int tid = threadIdx.x;
    int base = blockIdx.x * 1024;
    int v[4]; int s = 0;
    #pragma unroll
    for (int r = 0; r < 4; r++) {
        int idx = base + tid * 4 + r;
        v[r] = (idx < N) ? counts[idx] : 0;
        s += v[r];
    }
    sdata[tid] = s;
    __syncthreads();
    for (int o = 1; o < TPB; o <<= 1) {
        int t = (tid >= o) ? sdata[tid - o] : 0;
        __syncthreads();
        sdata[tid] += t;
        __syncthreads();
    }
    if (tid == TPB - 1) partials[blockIdx.x] = sdata[TPB - 1];
    int run = sdata[tid] - s;
    #pragma unroll
    for (int r = 0; r < 4; r++) {
        int idx = base + tid * 4 + r;
        if (idx < N) offs[idx] = run;
        run += v[r];
    }
}

__global__ void scan2_k(int* __restrict__ partials, int nPart) {
    if (blockIdx.x == 0 && threadIdx.x == 0) {
        int acc = 0;
        for (int i = 0; i < nPart; i++) { int t = partials[i]; partials[i] = acc; acc += t; }
    }
}

__global__ void scan3_k(int* __restrict__ offs, const int* __restrict__ partials, int N, int E) {
    int i = blockIdx.x * TPB + threadIdx.x;
    if (i < N) offs[i] += partials[i >> 10];
    else if (i == N) offs[N] = E;
}

__global__ void fill_k(const int* __restrict__ src, const int* __restrict__ dst,
                       const int* __restrict__ offs, int* __restrict__ cursor,
                       int* __restrict__ srcS, int* __restrict__ eOrigS, int E) {
    int e = blockIdx.x * TPB + threadIdx.x;
    if (e >= E) return;
    int d = dst[e];
    int p = offs[d] + atomicAdd(&cursor[d], 1);
    srcS[p] = src[e];
    eOrigS[p] = e;
}

// ================= h0 (bf16, dst-sorted order) — one-time =================
__global__ void h0s_k(const float* __restrict__ xa, const float* __restrict__ xb,
                      const float* __restrict__ efa, const float* __restrict__ efb,
                      const int* __restrict__ srcS, const int* __restrict__ eOrigS,
                      int Ea, int Eb, int Na, int E,
                      const float* __restrict__ W_in, const float* __restrict__ b_in,
                      __hip_bfloat16* __restrict__ h0s) {
    __shared__ float Wl[6 * 64];
    __shared__ float bl[64];
    for (int t = threadIdx.x; t < 6 * 64; t += TPB) Wl[t] = W_in[t];
    if (threadIdx.x < 64) bl[threadIdx.x] = b_in[threadIdx.x];
    __syncthreads();
    long long gid = (long long)blockIdx.x * TPB + threadIdx.x;
    if (gid >= (long long)E * 64) return;
    int k = (int)(gid >> 6), j = (int)(gid & 63);
    int e = eOrigS[k];
    int s = srcS[k];
    const float* xp = (s < Na) ? (xa + (size_t)s * 5) : (xb + (size_t)(s - Na) * 5);
    float efv = (e < Ea) ? efa[e] : ((e < Ea + Eb) ? efb[e - Ea] : 999.0f);
    float acc = bl[j];
    #pragma unroll
    for (int i = 0; i < 5; i++) acc += xp[i] * Wl[i * 64 + j];
    acc += efv * Wl[5 * 64 + j];
    acc = fmaxf(acc, 0.0f);
    h0s[(size_t)gid] = __float2bfloat16(acc);
}

// ================= W_msg -> MFMA B-fragment order (bf16) =================
__global__ void wfrag_k(const float* __restrict__ W_msg, __hip_bfloat16* __restrict__ Wf) {
    int t = blockIdx.x * TPB + threadIdx.x;
    if (t >= 4096) return;
    int j = t & 7, lane = (t >> 3) & 63, fi = t >> 9;
    int ct = fi >> 1, kt = fi & 1;
    int k = kt * 32 + (lane >> 4) * 8 + j;
    int col = ct * 16 + (lane & 15);
    Wf[t] = __float2bfloat16(W_msg[k * 64 + col]);
}

// ================= wave-per-node CSR aggregation: ONE 64B line per edge =================
// wave = node. lane: q = lane>>4 (edge slot 0..3), cq = lane&15 (channels 4cq..4cq+3).
// h0s: sequential bf16 (uint2/lane); aggW8: random fp8 row (uint/lane, 64B = 1 line).
// MODE 0: agg = segsum(h0);  MODE 1: segsum(relu(h0 + aggW));  MODE 2: +hsave
template<int MODE>
__global__ __launch_bounds__(TPB) void aggregate_k(const uint2* __restrict__ h0u2,
                                                   const unsigned* __restrict__ aggW8,
                                                   const int* __restrict__ srcS,
                                                   const int* __restrict__ eOrigS,
                                                   const int* __restrict__ offs,
                                                   uint2* __restrict__ aggB2,
                                                   float* __restrict__ hsave,
                                                   int N, int off) {
    int n = (blockIdx.x * TPB + threadIdx.x) >> 6;
    if (n >= N) return;
    int lane = threadIdx.x & 63;
    int q = lane >> 4, cq = lane & 15;
    int beg = offs[n], end = offs[n + 1];
    float a0 = 0.f, a1 = 0.f, a2 = 0.f, a3 = 0.f;
    for (int k = beg + q; k < end; k += 4) {
        uint2 hv = h0u2[(size_t)k * 16 + cq];
        float v0 = __uint_as_float(hv.x << 16);
        float v1 = __uint_as_float(hv.x & 0xffff0000u);
        float v2 = __uint_as_float(hv.y << 16);
        float v3 = __uint_as_float(hv.y & 0xffff0000u);
        if (MODE >= 1) {
            int s = srcS[k];
            unsigned w = aggW8[(size_t)s * 16 + cq];
            v0 = fmaxf(v0 + dec_fp8(w & 0xffu),         0.f);
            v1 = fmaxf(v1 + dec_fp8((w >> 8) & 0xffu),  0.f);
            v2 = fmaxf(v2 + dec_fp8((w >> 16) & 0xffu), 0.f);
            v3 = fmaxf(v3 + dec_fp8(w >> 24),           0.f);
        }
        if (MODE == 2) {
            int eo = eOrigS[k];
            if (eo >= off) {
                float4 hw; hw.x = v0; hw.y = v1; hw.z = v2; hw.w = v3;
                *(float4*)(hsave + (size_t)(eo - off) * 64 + 4 * cq) = hw;
            }
        }
        a0 += v0; a1 += v1; a2 += v2; a3 += v3;
    }
    a0 += __shfl_xor(a0, 16, 64); a0 += __shfl_xor(a0, 32, 64);
    a1 += __shfl_xor(a1, 16, 64); a1 += __shfl_xor(a1, 32, 64);
    a2 += __shfl_xor(a2, 16, 64); a2 += __shfl_xor(a2, 32, 64);
    a3 += __shfl_xor(a3, 16, 64); a3 += __shfl_xor(a3, 32, 64);
    if (q == 0)
        aggB2[(size_t)n * 16 + cq] = make_uint2(pack_bf16x2_rne(a0, a1),
                                                pack_bf16x2_rne(a2, a3));
}

// ================= MFMA node GEMM: aggW8(fp8) = aggB(bf16) @ W_msg + b_msg =================
__global__ __launch_bounds__(TPB) void nodegemm_k(const unsigned* __restrict__ aggB,
                                                  const __hip_bfloat16* __restrict__ Wf,
                                                  const float* __restrict__ b_msg,
                                                  unsigned* __restrict__ aggW8, int N) {
    int lane = threadIdx.x & 63;
    int wv = threadIdx.x >> 6;
    int n0w = blockIdx.x * 64 + wv * 16;
    int arow = lane & 15;
    int kq = lane >> 4;

    short8v bfr[8];
    #pragma unroll
    for (int fi = 0; fi < 8; fi++)
        bfr[fi] = *reinterpret_cast<const short8v*>(Wf + ((size_t)(fi * 64 + lane)) * 8);

    f32x4 acc[4];
    #pragma unroll
    for (int ct = 0; ct < 4; ct++) {
        float bias = b_msg[ct * 16 + arow];
        acc[ct][0] = bias; acc[ct][1] = bias; acc[ct][2] = bias; acc[ct][3] = bias;
    }

    short8v a0 = *reinterpret_cast<const short8v*>(aggB + (size_t)(n0w + arow) * 32 + kq * 4);
    short8v a1 = *reinterpret_cast<const short8v*>(aggB + (size_t)(n0w + arow) * 32 + 16 + kq * 4);

    #pragma unroll
    for (int ct = 0; ct < 4; ct++) {
        acc[ct] = __builtin_amdgcn_mfma_f32_16x16x32_bf16(a0, bfr[2 * ct + 0], acc[ct], 0, 0, 0);
        acc[ct] = __builtin_amdgcn_mfma_f32_16x16x32_bf16(a1, bfr[2 * ct + 1], acc[ct], 0, 0, 0);
    }

    // C/D: col = lane&15 (=arow), row = kq*4 + r. Assemble 4 fp8 bytes across arow quads.
    #pragma unroll
    for (int ct = 0; ct < 4; ct++) {
        #pragma unroll
        for (int r = 0; r < 4; r++) {
            unsigned u = enc_fp8(acc[ct][r]);
            u |= __shfl_xor(u, 1, 64) << 8;     // valid at arow%2==0: bytes arow, arow+1
            u |= __shfl_xor(u, 2, 64) << 16;    // valid at arow%4==0: bytes arow..arow+3
            int n = n0w + kq * 4 + r;
            if (((lane & 3) == 0) && n < N)
                aggW8[(size_t)n * 16 + ct * 4 + (arow >> 2)] = u;
        }
    }
}

// ================= node_h = relu([x, agg] @ W_node + b_node) =================
__global__ void nodeh_k(const float* __restrict__ xa, const float* __restrict__ xb,
                        int Na, int N,
                        const unsigned* __restrict__ aggB,
                        const float* __restrict__ W_node, const float* __restrict__ b_node,
                        float* __restrict__ node_h) {
    __shared__ float Wl[69 * 32];
    __shared__ float bl[32];
    for (int t = threadIdx.x; t < 69 * 32; t += TPB) Wl[t] = W_node[t];
    if (threadIdx.x < 32) bl[threadIdx.x] = b_node[threadIdx.x];
    __syncthreads();
    long long gid = (long long)blockIdx.x * TPB + threadIdx.x;
    if (gid >= (long long)N * 32) return;
    int n = (int)(gid >> 5), j = (int)(gid & 31);
    const float* xp = (n < Na) ? (xa + (size_t)n * 5) : (xb + (size_t)(n - Na) * 5);
    float acc = bl[j];
    #pragma unroll
    for (int i = 0; i < 5; i++) acc += xp[i] * Wl[i * 32 + j];
    const unsigned* ar = aggB + (size_t)n * 32;
    #pragma unroll
    for (int i2 = 0; i2 < 32; i2++) {
        unsigned u = ar[i2];
        acc += __uint_as_float(u << 16)         * Wl[(5 + 2 * i2)     * 32 + j];
        acc += __uint_as_float(u & 0xffff0000u) * Wl[(5 + 2 * i2 + 1) * 32 + j];
    }
    node_h[gid] = fmaxf(acc, 0.0f);
}

// ================= MLP head =================
#define TM2 32
#define MSTR 260

__device__ __forceinline__ void mlp_layer2(const float* __restrict__ W, const float* __restrict__ b,
                                           int in, int out, int lgout,
                                           const float* __restrict__ A, float* __restrict__ B) {
    int pairs = out * (TM2 / 8);
    const float4* a4b = (const float4*)A;
    for (int p = threadIdx.x; p < pairs; p += TPB) {
        int j = p & (out - 1);
        int r0 = (p >> lgout) * 8;
        float acc[8];
        float bj = b[j];
        #pragma unroll
        for (int r = 0; r < 8; r++) acc[r] = bj;
        for (int i4 = 0; i4 < (in >> 2); i4++) {
            int i = i4 * 4;
            float w0 = W[(i + 0) * out + j];
            float w1 = W[(i + 1) * out + j];
            float w2 = W[(i + 2) * out + j];
            float w3 = W[(i + 3) * out + j];
            #pragma unroll
            for (int r = 0; r < 8; r++) {
                float4 a = a4b[(r0 + r) * 65 + i4];
                acc[r] += a.x * w0 + a.y * w1 + a.z * w2 + a.w * w3;
            }
        }
        #pragma unroll
        for (int r = 0; r < 8; r++) B[(r0 + r) * MSTR + j] = fmaxf(acc[r], 0.0f);
    }
    __syncthreads();
}

__global__ __launch_bounds__(TPB) void mlp2_k(const float* __restrict__ node_h,
                                              const float* __restrict__ hsave,
                                              const int* __restrict__ pb, int NC, int Na,
                                              const float* __restrict__ W1, const float* __restrict__ b1,
                                              const float* __restrict__ W2, const float* __restrict__ b2,
                                              const float* __restrict__ W3, const float* __restrict__ b3,
                                              const float* __restrict__ W4, const float* __restrict__ b4,
                                              const float* __restrict__ W5, const float* __restrict__ b5,
                                              const float* __restrict__ W6, const float* __restrict__ b6,
                                              float* __restrict__ out) {
    __shared__ __align__(16) float A[TM2 * MSTR];
    __shared__ __align__(16) float B[TM2 * MSTR];
    int c0 = blockIdx.x * TM2;
    for (int idx = threadIdx.x; idx < TM2 * 128; idx += TPB) {
        int r = idx >> 7, col = idx & 127;
        int c = c0 + r;
        float v = 0.0f;
        if (c < NC) {
            if (col < 32) v = node_h[(size_t)pb[c] * 32 + col];
            else if (col < 64) v = node_h[(size_t)(Na + pb[NC + c]) * 32 + (col - 32)];
            else v = hsave[(size_t)c * 64 + (col - 64)] + hsave[(size_t)(NC + c) * 64 + (col - 64)];
        }
        A[r * MSTR + col] = v;
    }
    __syncthreads();
    mlp_layer2(W1, b1, 128, 128, 7, A, B);
    mlp_layer2(W2, b2, 128, 256, 8, B, A);
    mlp_layer2(W3, b3, 256, 256, 8, A, B);
    mlp_layer2(W4, b4, 256, 128, 7, B, A);
    mlp_layer2(W5, b5, 128, 64, 6, A, B);
    if (threadIdx.x < TM2) {
        int r = threadIdx.x, c = c0 + r;
        if (c < NC) {
            float z[4];
            #pragma unroll
            for (int k = 0; k < 4; k++) {
                float acc = b6[k];
                for (int i = 0; i < 64; i++) acc += B[r * MSTR + i] * W6[i * 4 + k];
                z[k] = acc;
            }
            float m = fmaxf(fmaxf(z[0], z[1]), fmaxf(z[2], z[3]));
            float e0 = expf(z[0] - m), e1 = expf(z[1] - m), e2 = expf(z[2] - m), e3 = expf(z[3] - m);
            float inv = 1.0f / (e0 + e1 + e2 + e3);
            int am = 0; float bm = z[0];
            if (z[1] > bm) { bm = z[1]; am = 1; }
            if (z[2] > bm) { bm = z[2]; am = 2; }
            if (z[3] > bm) { bm = z[3]; am = 3; }
            out[(size_t)c * 3 + 0] = (float)pb[c];
            out[(size_t)c * 3 + 1] = (float)pb[NC + c];
            out[(size_t)c * 3 + 2] = (float)am;
            float* po = out + (size_t)NC * 3 + (size_t)c * 4;
            po[0] = e0 * inv; po[1] = e1 * inv; po[2] = e2 * inv; po[3] = e3 * inv;
        }
    }
}

extern "C" void kernel_launch(void* const* d_in, const int* in_sizes, int n_in,
                              void* d_out, int out_size, void* d_ws, size_t ws_size,
                              hipStream_t stream) {
    const float* xa   = (const float*)d_in[0];
    const float* efa  = (const float*)d_in[1];
    const int*   ea   = (const int*)d_in[2];
    const float* xb   = (const float*)d_in[3];
    const float* efb  = (const float*)d_in[4];
    const int*   eb   = (const int*)d_in[5];
    const int*   pb   = (const int*)d_in[6];
    const float* W_in   = (const float*)d_in[7];
    const float* b_in   = (const float*)d_in[8];
    const float* W_msg  = (const float*)d_in[9];
    const float* b_msg  = (const float*)d_in[10];
    const float* W_node = (const float*)d_in[11];
    const float* b_node = (const float*)d_in[12];
    const float* W1 = (const float*)d_in[13]; const float* b1 = (const float*)d_in[14];
    const float* W2 = (const float*)d_in[15]; const float* b2 = (const float*)d_in[16];
    const float* W3 = (const float*)d_in[17]; const float* b3 = (const float*)d_in[18];
    const float* W4 = (const float*)d_in[19]; const float* b4 = (const float*)d_in[20];
    const float* W5 = (const float*)d_in[21]; const float* b5 = (const float*)d_in[22];
    const float* W6 = (const float*)d_in[23]; const float* b6 = (const float*)d_in[24];

    int Na = in_sizes[0] / 5;
    int Ea = in_sizes[2] / 2;
    int Nb = in_sizes[3] / 5;
    int Eb = in_sizes[5] / 2;
    int NC = in_sizes[6] / 2;
    int N = Na + Nb;
    int Npad = (N + 63) & ~63;
    int E = Ea + Eb + 2 * NC;
    int off = Ea + Eb;
    int nPart = (N + 1023) / 1024;

    char* p = (char*)d_ws;
    auto alloc = [&](size_t bytes) { char* r = p; p += (bytes + 255) & ~(size_t)255; return r; };
    int*   srcO   = (int*)alloc((size_t)E * 4);
    int*   dstO   = (int*)alloc((size_t)E * 4);
    int*   counts = (int*)alloc((size_t)N * 4);
    int*   offs   = (int*)alloc((size_t)(N + 1) * 4);
    int*   cursor = (int*)alloc((size_t)N * 4);
    int*   parts  = (int*)alloc((size_t)nPart * 4);
    int*   srcS   = (int*)alloc((size_t)E * 4);
    int*   eOrigS = (int*)alloc((size_t)E * 4);
    __hip_bfloat16* h0s = (__hip_bfloat16*)alloc((size_t)E * 64 * 2);
    unsigned* aggW8 = (unsigned*)alloc((size_t)Npad * 16 * 4);   // fp8 rows, 64B/node
    uint2* aggB2  = (uint2*)alloc((size_t)Npad * 16 * 8);        // bf16x2 packed
    __hip_bfloat16* Wf = (__hip_bfloat16*)alloc(4096 * 2);
    float* hsave  = (float*)alloc((size_t)2 * NC * 64 * 4);
    float* nodeh  = (float*)alloc((size_t)N * 32 * 4);
    if ((size_t)(p - (char*)d_ws) > ws_size) return;

    hipMemsetAsync(counts, 0, (size_t)N * 4, stream);
    hipMemsetAsync(cursor, 0, (size_t)N * 4, stream);

    build_edges_k<<<(E + TPB - 1) / TPB, TPB, 0, stream>>>(ea, eb, pb, Ea, Eb, NC, Na, srcO, dstO);
    count_k<<<(E + TPB - 1) / TPB, TPB, 0, stream>>>(dstO, counts, E);
    scan1_k<<<nPart, TPB, 0, stream>>>(counts, offs, parts, N);
    scan2_k<<<1, 64, 0, stream>>>(parts, nPart);
    scan3_k<<<(N + 1 + TPB - 1) / TPB, TPB, 0, stream>>>(offs, parts, N, E);
    fill_k<<<(E + TPB - 1) / TPB, TPB, 0, stream>>>(srcO, dstO, offs, cursor, srcS, eOrigS, E);

    h0s_k<<<(int)(((long long)E * 64 + TPB - 1) / TPB), TPB, 0, stream>>>(
        xa, xb, efa, efb, srcS, eOrigS, Ea, Eb, Na, E, W_in, b_in, h0s);
    wfrag_k<<<(4096 + TPB - 1) / TPB, TPB, 0, stream>>>(W_msg, Wf);

    int agrid = (N * 64 + TPB - 1) / TPB;   // 4 waves/block, wave = node
    int nblk = Npad / 64;
    const uint2* h0u2 = (const uint2*)h0s;
    const unsigned* aggBu = (const unsigned*)aggB2;

    aggregate_k<0><<<agrid, TPB, 0, stream>>>(h0u2, aggW8, srcS, eOrigS, offs,
                                              aggB2, nullptr, N, off);
    for (int t = 1; t <= 100; t++) {
        nodegemm_k<<<nblk, TPB, 0, stream>>>(aggBu, Wf, b_msg, aggW8, N);
        if (t < 100)
            aggregate_k<1><<<agrid, TPB, 0, stream>>>(h0u2, aggW8, srcS, eOrigS, offs,
                                                      aggB2, nullptr, N, off);
        else
            aggregate_k<2><<<agrid, TPB, 0, stream>>>(h0u2, aggW8, srcS, eOrigS, offs,
                                                      aggB2, hsave, N, off);
    }

    nodeh_k<<<(int)(((long long)N * 32 + TPB - 1) / TPB), TPB, 0, stream>>>(
        xa, xb, Na, N, aggBu, W_node, b_node, nodeh);
    mlp2_k<<<(NC + TM2 - 1) / TM2, TPB, 0, stream>>>(nodeh, hsave, pb, NC, Na,
                                                     W1, b1, W2, b2, W3, b3, W4, b4, W5, b5, W6, b6,
                                                     (float*)d_out);
}